// Round 2
// baseline (789.654 us; speedup 1.0000x reference)
//
#include <hip/hip_runtime.h>
#include <math.h>

#define Lseq 2048
// B=16, H=8, E=64, O=64, MODES=64
// Radix-4 DIF decomposition: all selected freqs f < 64, f = 4g + r.
// t = t' + 512 j, t' in [0,512):  e^{-2pi i f t/2048} = tw(t',f) * (-i)^{r j}
// y0 = x0+x1+x2+x3 (r=0), y2 = x0-x1+x2-x3 (r=2), y1 = p - i q, y3 = p + i q
// with p = x0-x2, q = x1-x3  (x_j = x[t'+512 j]).

// ---------------- workspace layout (bytes) ----------------
// twq [512][64] float2  256 KB   twiddles (cos, +sin) at freq index_q
// twk [512][64] float2  256 KB   twiddles at freq index_kv
// Gq  [16][8][64][64]c    4 MB
// Gk                      4 MB
// U                       4 MB
// A                       4 MB
// wc  [8][64][64][64] f2 16 MB
#define OFF_TWQ 0u
#define OFF_TWK (256u << 10)
#define OFF_GQ  (1u << 20)
#define OFF_GK  (5u << 20)
#define OFF_U   (9u << 20)
#define OFF_A   (13u << 20)
#define OFF_WC  (17u << 20)

// ---------------------------------------------------------------------------
__global__ __launch_bounds__(256) void k_twiddle(
    const int* __restrict__ iq, const int* __restrict__ ikv,
    float2* __restrict__ twq, float2* __restrict__ twk)
{
    int idx = blockIdx.x * 256 + threadIdx.x;   // 0 .. 512*64-1
    int t = idx >> 6;
    int m = idx & 63;
    const float w = 6.2831853071795864769f / (float)Lseq;
    float s, c;
    int ph = (t * iq[m]) & (Lseq - 1);
    sincosf(w * (float)ph, &s, &c);
    twq[idx] = make_float2(c, s);
    ph = (t * ikv[m]) & (Lseq - 1);
    sincosf(w * (float)ph, &s, &c);
    twk[idx] = make_float2(c, s);
}

// ---------------------------------------------------------------------------
// Transpose weights to wc[h][x][e][o]
__global__ __launch_bounds__(256) void k_wtrans(
    const float* __restrict__ w1, const float* __restrict__ w2,
    float2* __restrict__ wc)
{
    int h = blockIdx.x, e = blockIdx.y;
    const float* p1 = w1 + (((size_t)h * 64 + e) * 64) * 64;  // [o][x]
    const float* p2 = w2 + (((size_t)h * 64 + e) * 64) * 64;
    __shared__ float s1[64][65];
    __shared__ float s2[64][65];
    int tid = threadIdx.x;
    for (int i = tid; i < 1024; i += 256) {
        int o = i >> 4, xc = (i & 15) * 4;
        float4 a = *(const float4*)(p1 + o * 64 + xc);
        s1[o][xc] = a.x; s1[o][xc + 1] = a.y; s1[o][xc + 2] = a.z; s1[o][xc + 3] = a.w;
        float4 b = *(const float4*)(p2 + o * 64 + xc);
        s2[o][xc] = b.x; s2[o][xc + 1] = b.y; s2[o][xc + 2] = b.z; s2[o][xc + 3] = b.w;
    }
    __syncthreads();
    float2* dst = wc + ((size_t)h * 64) * 4096 + (size_t)e * 64;
    for (int i = tid; i < 4096; i += 256) {
        int x = i >> 6, o = i & 63;
        dst[(size_t)x * 4096 + o] = make_float2(s1[o][x], s2[o][x]);
    }
}

// ---------------------------------------------------------------------------
// Radix-4 partial DFT:
//  - grid (b, h, z): one block = full 512 t' for one signal. No split-K.
//  - 512 threads = 4 subs x 128; sub s owns t' in [128s, 128s+128), 16 rounds of 8.
//  - compute thread (eg,g8): e-tile 4, mode-octet 8*g8..8*g8+7 (2 quads),
//    96 accumulators; twiddles live in registers and rotate by delta_f =
//    tw-row[t=1] each t' step, re-initialized exactly from the table each
//    round (max 7 rotations -> ~4 ulp drift, below fp32 summation noise).
//  - y_s double-buffered (2x32KB): ONE barrier per round; next-round global
//    x loads + twiddle row issued at top of compute phase so the barrier's
//    vmcnt(0) drain finds them already complete.
//  - 4-sub tree reduce in LDS (aliases y_s), direct write to Gq/Gk.
__global__ __launch_bounds__(512, 2) void k_dft(
    const float* __restrict__ q, const float* __restrict__ k,
    const float* __restrict__ twq, const float* __restrict__ twk,
    float2* __restrict__ Gq, float2* __restrict__ Gk)
{
    int b = blockIdx.x, h = blockIdx.y, z = blockIdx.z;
    const float* src = z ? k : q;
    const float* tws = z ? twk : twq;

    __shared__ float y_s[2][4][8][4][64];    // 64 KB: [buf][sub][t'][comp][e]

    int tid = threadIdx.x;
    int sub = tid >> 7;            // t' quarter
    int st  = tid & 127;
    int tl  = st >> 4;             // staging row 0..7
    int e4q = st & 15;             // staging e-quad
    int eg  = st >> 3;             // compute e-group (4 e)
    int g8  = st & 7;              // compute mode-octet
    int tbase = sub * 128;

    const float* xbase = src + ((size_t)b * Lseq) * 512 + h * 64;
    const float* xrow0 = xbase + (size_t)(tbase + tl) * 512 + e4q * 4;

    // per-step rotation constants: delta_f = tw(t=1, f), exact from table
    const float* trow1 = tws + 128 + g8 * 16;
    float4 d0 = *(const float4*)(trow1);
    float4 d1 = *(const float4*)(trow1 + 4);
    float4 d2 = *(const float4*)(trow1 + 8);
    float4 d3 = *(const float4*)(trow1 + 12);
    float dc[8], dsn[8];
    dc[0] = d0.x; dsn[0] = d0.y; dc[1] = d0.z; dsn[1] = d0.w;
    dc[2] = d1.x; dsn[2] = d1.y; dc[3] = d1.z; dsn[3] = d1.w;
    dc[4] = d2.x; dsn[4] = d2.y; dc[5] = d2.z; dsn[5] = d2.w;
    dc[6] = d3.x; dsn[6] = d3.y; dc[7] = d3.z; dsn[7] = d3.w;

    float a[4][12], bb[4][12];
#pragma unroll
    for (int i = 0; i < 4; ++i)
#pragma unroll
        for (int j = 0; j < 12; ++j) { a[i][j] = 0.f; bb[i][j] = 0.f; }

    // prologue: round-0 x loads + twiddle row
    float4 c0 = *(const float4*)(xrow0);
    float4 c1 = *(const float4*)(xrow0 + 262144);
    float4 c2 = *(const float4*)(xrow0 + 524288);
    float4 c3 = *(const float4*)(xrow0 + 786432);
    const float* trow = tws + (size_t)tbase * 128 + g8 * 16;
    float4 tA = *(const float4*)(trow);
    float4 tB = *(const float4*)(trow + 4);
    float4 tC = *(const float4*)(trow + 8);
    float4 tD = *(const float4*)(trow + 12);
    float4 n0, n1, n2, n3, uA, uB, uC, uD;

    for (int rnd = 0; rnd < 16; ++rnd) {
        int buf = rnd & 1;
        {   // butterfly + stage into y_s[buf]
            float4 sa, sb, y0, y2, pp, qq;
            sa.x = c0.x + c2.x; sa.y = c0.y + c2.y; sa.z = c0.z + c2.z; sa.w = c0.w + c2.w;
            sb.x = c1.x + c3.x; sb.y = c1.y + c3.y; sb.z = c1.z + c3.z; sb.w = c1.w + c3.w;
            y0.x = sa.x + sb.x; y0.y = sa.y + sb.y; y0.z = sa.z + sb.z; y0.w = sa.w + sb.w;
            y2.x = sa.x - sb.x; y2.y = sa.y - sb.y; y2.z = sa.z - sb.z; y2.w = sa.w - sb.w;
            pp.x = c0.x - c2.x; pp.y = c0.y - c2.y; pp.z = c0.z - c2.z; pp.w = c0.w - c2.w;
            qq.x = c1.x - c3.x; qq.y = c1.y - c3.y; qq.z = c1.z - c3.z; qq.w = c1.w - c3.w;
            *(float4*)&y_s[buf][sub][tl][0][e4q * 4] = y0;
            *(float4*)&y_s[buf][sub][tl][1][e4q * 4] = y2;
            *(float4*)&y_s[buf][sub][tl][2][e4q * 4] = pp;
            *(float4*)&y_s[buf][sub][tl][3][e4q * 4] = qq;
        }
        __syncthreads();
        if (rnd < 15) {   // prefetch next round: latency hides under compute
            const float* p = xrow0 + (size_t)(rnd + 1) * (8 * 512);
            n0 = *(const float4*)(p);
            n1 = *(const float4*)(p + 262144);
            n2 = *(const float4*)(p + 524288);
            n3 = *(const float4*)(p + 786432);
            const float* tr = tws + (size_t)(tbase + (rnd + 1) * 8) * 128 + g8 * 16;
            uA = *(const float4*)(tr);
            uB = *(const float4*)(tr + 4);
            uC = *(const float4*)(tr + 8);
            uD = *(const float4*)(tr + 12);
        }
        // twiddle registers for this round (exact at t' = tbase + rnd*8)
        float wc_[8], ws_[8];
        wc_[0] = tA.x; ws_[0] = tA.y; wc_[1] = tA.z; ws_[1] = tA.w;
        wc_[2] = tB.x; ws_[2] = tB.y; wc_[3] = tB.z; ws_[3] = tB.w;
        wc_[4] = tC.x; ws_[4] = tC.y; wc_[5] = tC.z; ws_[5] = tC.w;
        wc_[6] = tD.x; ws_[6] = tD.y; wc_[7] = tD.z; ws_[7] = tD.w;
#pragma unroll
        for (int tt = 0; tt < 8; ++tt) {
            float4 Y0 = *(float4*)&y_s[buf][sub][tt][0][eg * 4];
            float4 Y2 = *(float4*)&y_s[buf][sub][tt][1][eg * 4];
            float4 Pv = *(float4*)&y_s[buf][sub][tt][2][eg * 4];
            float4 Qv = *(float4*)&y_s[buf][sub][tt][3][eg * 4];
            const float* y0a = (const float*)&Y0;
            const float* y2a = (const float*)&Y2;
            const float* pa  = (const float*)&Pv;
            const float* qa  = (const float*)&Qv;
#pragma unroll
            for (int i = 0; i < 4; ++i) {
                a[i][0]  += y0a[i] * wc_[0];  a[i][1]  += y0a[i] * ws_[0];
                a[i][2]  += y2a[i] * wc_[2];  a[i][3]  += y2a[i] * ws_[2];
                a[i][4]  += pa[i]  * wc_[1];  a[i][5]  += qa[i]  * ws_[1];
                a[i][6]  += pa[i]  * ws_[1];  a[i][7]  += qa[i]  * wc_[1];
                a[i][8]  += pa[i]  * wc_[3];  a[i][9]  += qa[i]  * ws_[3];
                a[i][10] += pa[i]  * ws_[3];  a[i][11] += qa[i]  * wc_[3];
                bb[i][0]  += y0a[i] * wc_[4];  bb[i][1]  += y0a[i] * ws_[4];
                bb[i][2]  += y2a[i] * wc_[6];  bb[i][3]  += y2a[i] * ws_[6];
                bb[i][4]  += pa[i]  * wc_[5];  bb[i][5]  += qa[i]  * ws_[5];
                bb[i][6]  += pa[i]  * ws_[5];  bb[i][7]  += qa[i]  * wc_[5];
                bb[i][8]  += pa[i]  * wc_[7];  bb[i][9]  += qa[i]  * ws_[7];
                bb[i][10] += pa[i]  * ws_[7];  bb[i][11] += qa[i]  * wc_[7];
            }
            if (tt < 7) {   // rotate all 8 twiddles one t' step
#pragma unroll
                for (int m = 0; m < 8; ++m) {
                    float c = wc_[m], s = ws_[m];
                    wc_[m] = c * dc[m] - s * dsn[m];
                    ws_[m] = s * dc[m] + c * dsn[m];
                }
            }
        }
        if (rnd < 15) {
            c0 = n0; c1 = n1; c2 = n2; c3 = n3;
            tA = uA; tB = uB; tC = uC; tD = uD;
        }
    }

    __syncthreads();   // y_s free for reduce

    // combine accumulators to complex G: per thread 4e x 8 modes = 16 float4
    float4 gvf[16];
#pragma unroll
    for (int i = 0; i < 4; ++i) {
        gvf[i * 4 + 0] = make_float4(a[i][0], -a[i][1], a[i][4] - a[i][5], -(a[i][6] + a[i][7]));
        gvf[i * 4 + 1] = make_float4(a[i][2], -a[i][3], a[i][8] + a[i][9], a[i][11] - a[i][10]);
        gvf[i * 4 + 2] = make_float4(bb[i][0], -bb[i][1], bb[i][4] - bb[i][5], -(bb[i][6] + bb[i][7]));
        gvf[i * 4 + 3] = make_float4(bb[i][2], -bb[i][3], bb[i][8] + bb[i][9], bb[i][11] - bb[i][10]);
    }

    // 4-sub tree reduce in LDS (XOR-swizzled float4 slots for full-rate banks)
    float4* red = (float4*)y_s;
    int rbase = ((sub >> 1) * 128 + st) * 16;
    int sx = st & 15;
    if (sub & 1) {
#pragma unroll
        for (int j = 0; j < 16; ++j) red[rbase + (j ^ sx)] = gvf[j];
    }
    __syncthreads();
    if (!(sub & 1)) {
#pragma unroll
        for (int j = 0; j < 16; ++j) {
            float4 r = red[rbase + (j ^ sx)];
            gvf[j].x += r.x; gvf[j].y += r.y; gvf[j].z += r.z; gvf[j].w += r.w;
        }
    }
    __syncthreads();
    if (sub == 2) {
#pragma unroll
        for (int j = 0; j < 16; ++j) red[st * 16 + (j ^ sx)] = gvf[j];
    }
    __syncthreads();
    if (sub == 0) {
#pragma unroll
        for (int j = 0; j < 16; ++j) {
            float4 r = red[st * 16 + (j ^ sx)];
            gvf[j].x += r.x; gvf[j].y += r.y; gvf[j].z += r.z; gvf[j].w += r.w;
        }
        float4* Gd4 = (float4*)((z ? Gk : Gq) + (size_t)(b * 8 + h) * 4096);
#pragma unroll
        for (int i = 0; i < 4; ++i)
#pragma unroll
            for (int j4 = 0; j4 < 4; ++j4)
                Gd4[(eg * 4 + i) * 32 + g8 * 4 + j4] = gvf[i * 4 + j4];
    }
}

// ---------------------------------------------------------------------------
// Per (b,h): freq-domain projection of q,k; S = Q^T K; tanh; U = T K.
__global__ __launch_bounds__(256) void k_core(
    const float2* __restrict__ Gq, const float2* __restrict__ Gk,
    const float* __restrict__ wqw, const float* __restrict__ wqb,
    const float* __restrict__ wkw, const float* __restrict__ wkb,
    const int* __restrict__ iq, const int* __restrict__ ikv,
    float2* __restrict__ U)
{
    int b = blockIdx.x, h = blockIdx.y;
    int tid = threadIdx.x;
    __shared__ float2 bufA[4096];
    __shared__ float2 Qf[4096];
    __shared__ float2 Kf[4096];
    __shared__ float  Wm[4096];
    __shared__ float  bias_s[64];
    __shared__ int    idx_s[64];

    size_t gb = (size_t)(b * 8 + h) * 4096;

    for (int z = 0; z < 2; ++z) {
        const float* Wsrc = z ? wkw : wqw;
        const float* bsrc = z ? wkb : wqb;
        const int*   isrc = z ? ikv : iq;
        const float2* Gsrc = (z ? Gk : Gq) + gb;
        float2* dst = z ? Kf : Qf;
        if (tid < 64) { bias_s[tid] = bsrc[tid]; idx_s[tid] = isrc[tid]; }
#pragma unroll
        for (int j = 0; j < 4; ++j)
            ((float4*)Wm)[tid + 256 * j] = ((const float4*)Wsrc)[tid + 256 * j];
#pragma unroll
        for (int j = 0; j < 8; ++j)
            ((float4*)bufA)[tid + 256 * j] = ((const float4*)Gsrc)[tid + 256 * j];
        __syncthreads();
        {
            int eg = tid >> 4, xg = tid & 15;
            float2 acc[4][4];
#pragma unroll
            for (int i = 0; i < 4; ++i)
#pragma unroll
                for (int j = 0; j < 4; ++j) acc[i][j] = make_float2(0.f, 0.f);
            for (int ep = 0; ep < 64; ++ep) {
                float wv[4]; float2 gvv[4];
#pragma unroll
                for (int i = 0; i < 4; ++i) wv[i] = Wm[(eg * 4 + i) * 64 + ep];
#pragma unroll
                for (int j = 0; j < 4; ++j) gvv[j] = bufA[ep * 64 + xg + 16 * j];
#pragma unroll
                for (int i = 0; i < 4; ++i)
#pragma unroll
                    for (int j = 0; j < 4; ++j) {
                        acc[i][j].x += wv[i] * gvv[j].x;
                        acc[i][j].y += wv[i] * gvv[j].y;
                    }
            }
#pragma unroll
            for (int j = 0; j < 4; ++j) {
                int x = xg + 16 * j;
                float bz = (idx_s[x] == 0) ? 2048.0f : 0.0f;
#pragma unroll
                for (int i = 0; i < 4; ++i) {
                    float2 v = acc[i][j];
                    v.x += bz * bias_s[eg * 4 + i];
                    dst[(eg * 4 + i) * 64 + x] = v;
                }
            }
        }
        __syncthreads();
    }

    {
        int xg = tid & 15, yg = tid >> 4;
        float2 acc[4][4];
#pragma unroll
        for (int i = 0; i < 4; ++i)
#pragma unroll
            for (int j = 0; j < 4; ++j) acc[i][j] = make_float2(0.f, 0.f);
        for (int e = 0; e < 64; ++e) {
            float2 qv[4], kv[4];
#pragma unroll
            for (int i = 0; i < 4; ++i) qv[i] = Qf[e * 64 + xg + 16 * i];
#pragma unroll
            for (int j = 0; j < 4; ++j) kv[j] = Kf[e * 64 + yg * 4 + j];
#pragma unroll
            for (int i = 0; i < 4; ++i)
#pragma unroll
                for (int j = 0; j < 4; ++j) {
                    acc[i][j].x += qv[i].x * kv[j].x - qv[i].y * kv[j].y;
                    acc[i][j].y += qv[i].x * kv[j].y + qv[i].y * kv[j].x;
                }
        }
#pragma unroll
        for (int i = 0; i < 4; ++i)
#pragma unroll
            for (int j = 0; j < 4; ++j)
                bufA[(yg * 4 + j) * 64 + xg + 16 * i] =
                    make_float2(tanhf(acc[i][j].x), tanhf(acc[i][j].y));
    }
    __syncthreads();

    {
        int xg = tid & 15, eg = tid >> 4;
        float2 acc[4][4];
#pragma unroll
        for (int i = 0; i < 4; ++i)
#pragma unroll
            for (int j = 0; j < 4; ++j) acc[i][j] = make_float2(0.f, 0.f);
        for (int y = 0; y < 64; ++y) {
            float2 kv[4], tv[4];
#pragma unroll
            for (int i = 0; i < 4; ++i) kv[i] = Kf[(eg * 4 + i) * 64 + y];
#pragma unroll
            for (int j = 0; j < 4; ++j) tv[j] = bufA[y * 64 + xg + 16 * j];
#pragma unroll
            for (int i = 0; i < 4; ++i)
#pragma unroll
                for (int j = 0; j < 4; ++j) {
                    acc[i][j].x += tv[j].x * kv[i].x - tv[j].y * kv[i].y;
                    acc[i][j].y += tv[j].x * kv[i].y + tv[j].y * kv[i].x;
                }
        }
        float2* Ud = U + gb;
#pragma unroll
        for (int i = 0; i < 4; ++i)
#pragma unroll
            for (int j = 0; j < 4; ++j)
                Ud[(eg * 4 + i) * 64 + xg + 16 * j] = acc[i][j];
    }
}

// ---------------------------------------------------------------------------
// Per (h,x): X[b,o] = sum_e U[b,e] wc[e,o]; fold irfft scales; A[b][h][o][x]=(P,Q).
__global__ __launch_bounds__(128) void k_apply_w(
    const float2* __restrict__ U, const float2* __restrict__ wc,
    const int* __restrict__ iq, float2* __restrict__ A)
{
    int x = blockIdx.x, h = blockIdx.y;
    int tid = threadIdx.x;
    __shared__ float2 wl[4096];
    __shared__ float2 ul[16][65];
    const float4* wsrc = (const float4*)(wc + (size_t)(h * 64 + x) * 4096);
#pragma unroll
    for (int j = 0; j < 16; ++j)
        ((float4*)wl)[tid + 128 * j] = wsrc[tid + 128 * j];
#pragma unroll
    for (int j = 0; j < 8; ++j) {
        int idx = tid + 128 * j;
        int bb = idx >> 6, e = idx & 63;
        ul[bb][e] = U[((size_t)(bb * 8 + h) * 64 + e) * 64 + x];
    }
    __syncthreads();
    int bb = tid >> 3, og = tid & 7;
    float2 acc[8];
#pragma unroll
    for (int j = 0; j < 8; ++j) acc[j] = make_float2(0.f, 0.f);
    for (int e = 0; e < 64; ++e) {
        float2 u = ul[bb][e];
#pragma unroll
        for (int j = 0; j < 8; ++j) {
            float2 wv = wl[e * 64 + og + 8 * j];
            acc[j].x += u.x * wv.x - u.y * wv.y;
            acc[j].y += u.x * wv.y + u.y * wv.x;
        }
    }
    int f = iq[x];
    bool dc = (f == 0) || (2 * f == Lseq);
    float cm = (dc ? 1.0f : 2.0f) * (1.0f / (2048.0f * 262144.0f));
    float2* Ad = A + (size_t)(bb * 8 + h) * 4096;
#pragma unroll
    for (int j = 0; j < 8; ++j) {
        int o = og + 8 * j;
        Ad[o * 64 + x] = make_float2(cm * acc[j].x, dc ? 0.0f : -cm * acc[j].y);
    }
}

// ---------------------------------------------------------------------------
// Radix-4 inverse: out[t'+512j] from U_r/V_r class sums.
// grid (tt:8, h, b), 512 thr: wave = o-slice of 8 (A reads wave-uniform),
// lane = t'. tw tile XOR-swizzled by row (2-way max conflicts).
__global__ __launch_bounds__(512) void k_irfft(
    const float2* __restrict__ A, const float* __restrict__ tw,
    float* __restrict__ out)
{
    int tt = blockIdx.x, h = blockIdx.y, b = blockIdx.z;
    int t0 = tt * 64;
    int tid = threadIdx.x;
    __shared__ float2 A_s[4096];        // [o][x] (P,Q)
    __shared__ float  tw_s[64][128];    // rows t', XOR-swizzled float4s
    const float4* asrc = (const float4*)(A + (size_t)(b * 8 + h) * 4096);
#pragma unroll
    for (int j = 0; j < 4; ++j)
        ((float4*)A_s)[tid + 512 * j] = asrc[tid + 512 * j];
    {
        int row = tid >> 3, c4b = (tid & 7) * 4;
        const float4* s = (const float4*)(tw + (size_t)(t0 + row) * 128);
        float4* drow = (float4*)&tw_s[row][0];
#pragma unroll
        for (int kk = 0; kk < 4; ++kk) {
            int c4 = c4b + kk;
            drow[c4 ^ (row & 31)] = s[c4];
        }
    }
    __syncthreads();
    int tl = tid & 63, ow = tid >> 6;    // o = ow*8 + i
    float U0[8], U1[8], V1[8], U2[8], U3[8], V3[8];
#pragma unroll
    for (int i = 0; i < 8; ++i) { U0[i]=U1[i]=V1[i]=U2[i]=U3[i]=V3[i]=0.f; }
    const float4* trow = (const float4*)&tw_s[tl][0];
    int sw = tl & 31;
#pragma unroll
    for (int g = 0; g < 16; ++g) {
        float4 w0 = trow[(2 * g) ^ sw];       // c(4g),s(4g),c(4g+1),s(4g+1)
        float4 w1 = trow[(2 * g + 1) ^ sw];   // c(4g+2),s(4g+2),c(4g+3),s(4g+3)
#pragma unroll
        for (int i = 0; i < 8; ++i) {
            const float4* ap = (const float4*)&A_s[(ow * 8 + i) * 64 + 4 * g];
            float4 a0 = ap[0];   // P0,Q0,P1,Q1
            float4 a1 = ap[1];   // P2,Q2,P3,Q3
            U0[i] += a0.x * w0.x + a0.y * w0.y;
            U1[i] += a0.z * w0.z + a0.w * w0.w;
            V1[i] += a0.w * w0.z - a0.z * w0.w;
            U2[i] += a1.x * w1.x + a1.y * w1.y;
            U3[i] += a1.z * w1.z + a1.w * w1.w;
            V3[i] += a1.w * w1.z - a1.z * w1.w;
        }
    }
    float* op = out + ((size_t)(b * 8 + h) * 64 + ow * 8) * Lseq + t0 + tl;
#pragma unroll
    for (int i = 0; i < 8; ++i) {
        float u0 = U0[i], u1 = U1[i], v1 = V1[i], u2 = U2[i], u3 = U3[i], v3 = V3[i];
        op[(size_t)i * Lseq +    0] = u0 + u1 + u2 + u3;
        op[(size_t)i * Lseq +  512] = u0 + v1 - u2 - v3;
        op[(size_t)i * Lseq + 1024] = u0 - u1 + u2 - u3;
        op[(size_t)i * Lseq + 1536] = u0 - v1 - u2 + v3;
    }
}

// ---------------------------------------------------------------------------
extern "C" void kernel_launch(void* const* d_in, const int* in_sizes, int n_in,
                              void* d_out, int out_size, void* d_ws, size_t ws_size,
                              hipStream_t stream)
{
    const float* q    = (const float*)d_in[0];
    const float* k    = (const float*)d_in[1];
    const float* wq_w = (const float*)d_in[3];
    const float* wq_b = (const float*)d_in[4];
    const float* wk_w = (const float*)d_in[5];
    const float* wk_b = (const float*)d_in[6];
    const float* w1   = (const float*)d_in[9];
    const float* w2   = (const float*)d_in[10];
    const int*   iq   = (const int*)d_in[11];
    const int*   ikv  = (const int*)d_in[12];
    float* out = (float*)d_out;

    char* ws = (char*)d_ws;
    float2* twq = (float2*)(ws + OFF_TWQ);
    float2* twk = (float2*)(ws + OFF_TWK);
    float2* Gq  = (float2*)(ws + OFF_GQ);
    float2* Gk  = (float2*)(ws + OFF_GK);
    float2* Uw  = (float2*)(ws + OFF_U);
    float2* Aw  = (float2*)(ws + OFF_A);
    float2* wc  = (float2*)(ws + OFF_WC);

    k_twiddle<<<128, 256, 0, stream>>>(iq, ikv, twq, twk);
    k_dft<<<dim3(16, 8, 2), 512, 0, stream>>>(q, k, (const float*)twq,
                                              (const float*)twk, Gq, Gk);
    k_core<<<dim3(16, 8), 256, 0, stream>>>(Gq, Gk, wq_w, wq_b, wk_w, wk_b,
                                            iq, ikv, Uw);
    k_wtrans<<<dim3(8, 64), 256, 0, stream>>>(w1, w2, wc);
    k_apply_w<<<dim3(64, 8), 128, 0, stream>>>(Uw, wc, iq, Aw);
    k_irfft<<<dim3(8, 8, 16), 512, 0, stream>>>(Aw, (const float*)twq, out);
}

// Round 5
// 741.996 us; speedup vs baseline: 1.0642x; 1.0642x over previous
//
#include <hip/hip_runtime.h>
#include <math.h>

#define Lseq 2048
// B=16, H=8, E=64, O=64, MODES=64
// Radix-4 DIF decomposition: all selected freqs f < 64, f = 4g + r.
// t = t' + 512 j, t' in [0,512):  e^{-2pi i f t/2048} = tw(t',f) * (-i)^{r j}
// y0 = x0+x1+x2+x3 (r=0), y2 = x0-x1+x2-x3 (r=2), y1 = p - i q, y3 = p + i q
// with p = x0-x2, q = x1-x3  (x_j = x[t'+512 j]).

// ---------------- workspace layout (bytes) ----------------
// twq [512][64] float2  256 KB   twiddles (cos, +sin) at freq index_q
// twk [512][64] float2  256 KB   twiddles at freq index_kv
// Gq  [16][8][64][64]c    4 MB
// Gk                      4 MB
// U                       4 MB
// A                       4 MB
// wc  [8][64][64][64] f2 16 MB
#define OFF_TWQ 0u
#define OFF_TWK (256u << 10)
#define OFF_GQ  (1u << 20)
#define OFF_GK  (5u << 20)
#define OFF_U   (9u << 20)
#define OFF_A   (13u << 20)
#define OFF_WC  (17u << 20)

// ---------------------------------------------------------------------------
__global__ __launch_bounds__(256) void k_twiddle(
    const int* __restrict__ iq, const int* __restrict__ ikv,
    float2* __restrict__ twq, float2* __restrict__ twk)
{
    int idx = blockIdx.x * 256 + threadIdx.x;   // 0 .. 512*64-1
    int t = idx >> 6;
    int m = idx & 63;
    const float w = 6.2831853071795864769f / (float)Lseq;
    float s, c;
    int ph = (t * iq[m]) & (Lseq - 1);
    sincosf(w * (float)ph, &s, &c);
    twq[idx] = make_float2(c, s);
    ph = (t * ikv[m]) & (Lseq - 1);
    sincosf(w * (float)ph, &s, &c);
    twk[idx] = make_float2(c, s);
}

// ---------------------------------------------------------------------------
// Transpose weights to wc[h][x][e][o]
__global__ __launch_bounds__(256) void k_wtrans(
    const float* __restrict__ w1, const float* __restrict__ w2,
    float2* __restrict__ wc)
{
    int h = blockIdx.x, e = blockIdx.y;
    const float* p1 = w1 + (((size_t)h * 64 + e) * 64) * 64;  // [o][x]
    const float* p2 = w2 + (((size_t)h * 64 + e) * 64) * 64;
    __shared__ float s1[64][65];
    __shared__ float s2[64][65];
    int tid = threadIdx.x;
    for (int i = tid; i < 1024; i += 256) {
        int o = i >> 4, xc = (i & 15) * 4;
        float4 a = *(const float4*)(p1 + o * 64 + xc);
        s1[o][xc] = a.x; s1[o][xc + 1] = a.y; s1[o][xc + 2] = a.z; s1[o][xc + 3] = a.w;
        float4 b = *(const float4*)(p2 + o * 64 + xc);
        s2[o][xc] = b.x; s2[o][xc + 1] = b.y; s2[o][xc + 2] = b.z; s2[o][xc + 3] = b.w;
    }
    __syncthreads();
    float2* dst = wc + ((size_t)h * 64) * 4096 + (size_t)e * 64;
    for (int i = tid; i < 4096; i += 256) {
        int x = i >> 6, o = i & 63;
        dst[(size_t)x * 4096 + o] = make_float2(s1[o][x], s2[o][x]);
    }
}

// ---------------------------------------------------------------------------
// Radix-4 partial DFT:
//  - grid (b, h, z): one block = full 512 t' for one signal. No split-K.
//  - OCCUPANCY/VGPR BUDGET: y_s padded to 96 KB so LDS fits only 1 block/CU
//    -> backend occupancy target = 8 waves/CU = 2 waves/EU -> 256-VGPR
//    budget for the ~200-reg live set, no spill. (v2 used 64 KB LDS: 2
//    blocks/CU -> 4 waves/EU target -> 128-VGPR budget -> ~70 regs spilled,
//    1.8 GB scratch traffic, 515 us. Grid is 256 blocks = 1/CU, so the
//    padding costs zero occupancy.)
//  - 512 threads = 4 subs x 128; sub s owns t' in [128s, 128s+128), 16 rounds of 8.
//  - compute thread (eg,g8): e-tile 4, mode-octet 8*g8..8*g8+7 (2 quads),
//    96 accumulators; twiddles live in registers and rotate by delta_f =
//    tw-row[t=1] each t' step, re-initialized exactly from the table each
//    round (max 7 rotations -> ~4 ulp drift, below fp32 summation noise).
//  - y_s double-buffered: ONE barrier per round; next-round global x loads +
//    twiddle row issued right after the barrier so latency hides under the
//    8-tt compute block.
//  - 4-sub tree reduce in LDS (aliases y_s), direct write to Gq/Gk.
#define EPAD 96   // padded e-row (64 data + 32 pad): 2*4*8*4*96*4B = 96 KB
__global__ __launch_bounds__(512) void k_dft(
    const float* __restrict__ q, const float* __restrict__ k,
    const float* __restrict__ twq, const float* __restrict__ twk,
    float2* __restrict__ Gq, float2* __restrict__ Gk)
{
    int b = blockIdx.x, h = blockIdx.y, z = blockIdx.z;
    const float* src = z ? k : q;
    const float* tws = z ? twk : twq;

    __shared__ float y_s[2][4][8][4][EPAD];    // 96 KB: [buf][sub][t'][comp][e]

    int tid = threadIdx.x;
    int sub = tid >> 7;            // t' quarter
    int st  = tid & 127;
    int tl  = st >> 4;             // staging row 0..7
    int e4q = st & 15;             // staging e-quad
    int eg  = st >> 3;             // compute e-group (4 e)
    int g8  = st & 7;              // compute mode-octet
    int tbase = sub * 128;

    const float* xbase = src + ((size_t)b * Lseq) * 512 + h * 64;
    const float* xrow0 = xbase + (size_t)(tbase + tl) * 512 + e4q * 4;

    // per-step rotation constants: delta_f = tw(t=1, f), exact from table
    const float* trow1 = tws + 128 + g8 * 16;
    float4 d0 = *(const float4*)(trow1);
    float4 d1 = *(const float4*)(trow1 + 4);
    float4 d2 = *(const float4*)(trow1 + 8);
    float4 d3 = *(const float4*)(trow1 + 12);
    float dc[8], dsn[8];
    dc[0] = d0.x; dsn[0] = d0.y; dc[1] = d0.z; dsn[1] = d0.w;
    dc[2] = d1.x; dsn[2] = d1.y; dc[3] = d1.z; dsn[3] = d1.w;
    dc[4] = d2.x; dsn[4] = d2.y; dc[5] = d2.z; dsn[5] = d2.w;
    dc[6] = d3.x; dsn[6] = d3.y; dc[7] = d3.z; dsn[7] = d3.w;

    float a[4][12], bb[4][12];
#pragma unroll
    for (int i = 0; i < 4; ++i)
#pragma unroll
        for (int j = 0; j < 12; ++j) { a[i][j] = 0.f; bb[i][j] = 0.f; }

    // prologue: round-0 x loads + twiddle row
    float4 c0 = *(const float4*)(xrow0);
    float4 c1 = *(const float4*)(xrow0 + 262144);
    float4 c2 = *(const float4*)(xrow0 + 524288);
    float4 c3 = *(const float4*)(xrow0 + 786432);
    const float* trow = tws + (size_t)tbase * 128 + g8 * 16;
    float4 tA = *(const float4*)(trow);
    float4 tB = *(const float4*)(trow + 4);
    float4 tC = *(const float4*)(trow + 8);
    float4 tD = *(const float4*)(trow + 12);
    float4 n0, n1, n2, n3, uA, uB, uC, uD;

    for (int rnd = 0; rnd < 16; ++rnd) {
        int buf = rnd & 1;
        {   // butterfly + stage into y_s[buf]
            float4 sa, sb, y0, y2, pp, qq;
            sa.x = c0.x + c2.x; sa.y = c0.y + c2.y; sa.z = c0.z + c2.z; sa.w = c0.w + c2.w;
            sb.x = c1.x + c3.x; sb.y = c1.y + c3.y; sb.z = c1.z + c3.z; sb.w = c1.w + c3.w;
            y0.x = sa.x + sb.x; y0.y = sa.y + sb.y; y0.z = sa.z + sb.z; y0.w = sa.w + sb.w;
            y2.x = sa.x - sb.x; y2.y = sa.y - sb.y; y2.z = sa.z - sb.z; y2.w = sa.w - sb.w;
            pp.x = c0.x - c2.x; pp.y = c0.y - c2.y; pp.z = c0.z - c2.z; pp.w = c0.w - c2.w;
            qq.x = c1.x - c3.x; qq.y = c1.y - c3.y; qq.z = c1.z - c3.z; qq.w = c1.w - c3.w;
            *(float4*)&y_s[buf][sub][tl][0][e4q * 4] = y0;
            *(float4*)&y_s[buf][sub][tl][1][e4q * 4] = y2;
            *(float4*)&y_s[buf][sub][tl][2][e4q * 4] = pp;
            *(float4*)&y_s[buf][sub][tl][3][e4q * 4] = qq;
        }
        __syncthreads();
        if (rnd < 15) {   // prefetch next round: latency hides under compute
            const float* p = xrow0 + (size_t)(rnd + 1) * (8 * 512);
            n0 = *(const float4*)(p);
            n1 = *(const float4*)(p + 262144);
            n2 = *(const float4*)(p + 524288);
            n3 = *(const float4*)(p + 786432);
            const float* tr = tws + (size_t)(tbase + (rnd + 1) * 8) * 128 + g8 * 16;
            uA = *(const float4*)(tr);
            uB = *(const float4*)(tr + 4);
            uC = *(const float4*)(tr + 8);
            uD = *(const float4*)(tr + 12);
        }
        // twiddle registers for this round (exact at t' = tbase + rnd*8)
        float wc_[8], ws_[8];
        wc_[0] = tA.x; ws_[0] = tA.y; wc_[1] = tA.z; ws_[1] = tA.w;
        wc_[2] = tB.x; ws_[2] = tB.y; wc_[3] = tB.z; ws_[3] = tB.w;
        wc_[4] = tC.x; ws_[4] = tC.y; wc_[5] = tC.z; ws_[5] = tC.w;
        wc_[6] = tD.x; ws_[6] = tD.y; wc_[7] = tD.z; ws_[7] = tD.w;
#pragma unroll
        for (int tt = 0; tt < 8; ++tt) {
            float4 Y0 = *(float4*)&y_s[buf][sub][tt][0][eg * 4];
            float4 Y2 = *(float4*)&y_s[buf][sub][tt][1][eg * 4];
            float4 Pv = *(float4*)&y_s[buf][sub][tt][2][eg * 4];
            float4 Qv = *(float4*)&y_s[buf][sub][tt][3][eg * 4];
            const float* y0a = (const float*)&Y0;
            const float* y2a = (const float*)&Y2;
            const float* pa  = (const float*)&Pv;
            const float* qa  = (const float*)&Qv;
#pragma unroll
            for (int i = 0; i < 4; ++i) {
                a[i][0]  += y0a[i] * wc_[0];  a[i][1]  += y0a[i] * ws_[0];
                a[i][2]  += y2a[i] * wc_[2];  a[i][3]  += y2a[i] * ws_[2];
                a[i][4]  += pa[i]  * wc_[1];  a[i][5]  += qa[i]  * ws_[1];
                a[i][6]  += pa[i]  * ws_[1];  a[i][7]  += qa[i]  * wc_[1];
                a[i][8]  += pa[i]  * wc_[3];  a[i][9]  += qa[i]  * ws_[3];
                a[i][10] += pa[i]  * ws_[3];  a[i][11] += qa[i]  * wc_[3];
                bb[i][0]  += y0a[i] * wc_[4];  bb[i][1]  += y0a[i] * ws_[4];
                bb[i][2]  += y2a[i] * wc_[6];  bb[i][3]  += y2a[i] * ws_[6];
                bb[i][4]  += pa[i]  * wc_[5];  bb[i][5]  += qa[i]  * ws_[5];
                bb[i][6]  += pa[i]  * ws_[5];  bb[i][7]  += qa[i]  * wc_[5];
                bb[i][8]  += pa[i]  * wc_[7];  bb[i][9]  += qa[i]  * ws_[7];
                bb[i][10] += pa[i]  * ws_[7];  bb[i][11] += qa[i]  * wc_[7];
            }
            if (tt < 7) {   // rotate all 8 twiddles one t' step
#pragma unroll
                for (int m = 0; m < 8; ++m) {
                    float c = wc_[m], s = ws_[m];
                    wc_[m] = c * dc[m] - s * dsn[m];
                    ws_[m] = s * dc[m] + c * dsn[m];
                }
            }
        }
        if (rnd < 15) {
            c0 = n0; c1 = n1; c2 = n2; c3 = n3;
            tA = uA; tB = uB; tC = uC; tD = uD;
        }
    }

    __syncthreads();   // y_s free for reduce

    // combine accumulators to complex G: per thread 4e x 8 modes = 16 float4
    float4 gvf[16];
#pragma unroll
    for (int i = 0; i < 4; ++i) {
        gvf[i * 4 + 0] = make_float4(a[i][0], -a[i][1], a[i][4] - a[i][5], -(a[i][6] + a[i][7]));
        gvf[i * 4 + 1] = make_float4(a[i][2], -a[i][3], a[i][8] + a[i][9], a[i][11] - a[i][10]);
        gvf[i * 4 + 2] = make_float4(bb[i][0], -bb[i][1], bb[i][4] - bb[i][5], -(bb[i][6] + bb[i][7]));
        gvf[i * 4 + 3] = make_float4(bb[i][2], -bb[i][3], bb[i][8] + bb[i][9], bb[i][11] - bb[i][10]);
    }

    // 4-sub tree reduce in LDS (XOR-swizzled float4 slots for full-rate banks)
    float4* red = (float4*)y_s;
    int rbase = ((sub >> 1) * 128 + st) * 16;
    int sx = st & 15;
    if (sub & 1) {
#pragma unroll
        for (int j = 0; j < 16; ++j) red[rbase + (j ^ sx)] = gvf[j];
    }
    __syncthreads();
    if (!(sub & 1)) {
#pragma unroll
        for (int j = 0; j < 16; ++j) {
            float4 r = red[rbase + (j ^ sx)];
            gvf[j].x += r.x; gvf[j].y += r.y; gvf[j].z += r.z; gvf[j].w += r.w;
        }
    }
    __syncthreads();
    if (sub == 2) {
#pragma unroll
        for (int j = 0; j < 16; ++j) red[st * 16 + (j ^ sx)] = gvf[j];
    }
    __syncthreads();
    if (sub == 0) {
#pragma unroll
        for (int j = 0; j < 16; ++j) {
            float4 r = red[st * 16 + (j ^ sx)];
            gvf[j].x += r.x; gvf[j].y += r.y; gvf[j].z += r.z; gvf[j].w += r.w;
        }
        float4* Gd4 = (float4*)((z ? Gk : Gq) + (size_t)(b * 8 + h) * 4096);
#pragma unroll
        for (int i = 0; i < 4; ++i)
#pragma unroll
            for (int j4 = 0; j4 < 4; ++j4)
                Gd4[(eg * 4 + i) * 32 + g8 * 4 + j4] = gvf[i * 4 + j4];
    }
}

// ---------------------------------------------------------------------------
// Per (b,h): freq-domain projection of q,k; S = Q^T K; tanh; U = T K.
__global__ __launch_bounds__(256) void k_core(
    const float2* __restrict__ Gq, const float2* __restrict__ Gk,
    const float* __restrict__ wqw, const float* __restrict__ wqb,
    const float* __restrict__ wkw, const float* __restrict__ wkb,
    const int* __restrict__ iq, const int* __restrict__ ikv,
    float2* __restrict__ U)
{
    int b = blockIdx.x, h = blockIdx.y;
    int tid = threadIdx.x;
    __shared__ float2 bufA[4096];
    __shared__ float2 Qf[4096];
    __shared__ float2 Kf[4096];
    __shared__ float  Wm[4096];
    __shared__ float  bias_s[64];
    __shared__ int    idx_s[64];

    size_t gb = (size_t)(b * 8 + h) * 4096;

    for (int z = 0; z < 2; ++z) {
        const float* Wsrc = z ? wkw : wqw;
        const float* bsrc = z ? wkb : wqb;
        const int*   isrc = z ? ikv : iq;
        const float2* Gsrc = (z ? Gk : Gq) + gb;
        float2* dst = z ? Kf : Qf;
        if (tid < 64) { bias_s[tid] = bsrc[tid]; idx_s[tid] = isrc[tid]; }
#pragma unroll
        for (int j = 0; j < 4; ++j)
            ((float4*)Wm)[tid + 256 * j] = ((const float4*)Wsrc)[tid + 256 * j];
#pragma unroll
        for (int j = 0; j < 8; ++j)
            ((float4*)bufA)[tid + 256 * j] = ((const float4*)Gsrc)[tid + 256 * j];
        __syncthreads();
        {
            int eg = tid >> 4, xg = tid & 15;
            float2 acc[4][4];
#pragma unroll
            for (int i = 0; i < 4; ++i)
#pragma unroll
                for (int j = 0; j < 4; ++j) acc[i][j] = make_float2(0.f, 0.f);
            for (int ep = 0; ep < 64; ++ep) {
                float wv[4]; float2 gvv[4];
#pragma unroll
                for (int i = 0; i < 4; ++i) wv[i] = Wm[(eg * 4 + i) * 64 + ep];
#pragma unroll
                for (int j = 0; j < 4; ++j) gvv[j] = bufA[ep * 64 + xg + 16 * j];
#pragma unroll
                for (int i = 0; i < 4; ++i)
#pragma unroll
                    for (int j = 0; j < 4; ++j) {
                        acc[i][j].x += wv[i] * gvv[j].x;
                        acc[i][j].y += wv[i] * gvv[j].y;
                    }
            }
#pragma unroll
            for (int j = 0; j < 4; ++j) {
                int x = xg + 16 * j;
                float bz = (idx_s[x] == 0) ? 2048.0f : 0.0f;
#pragma unroll
                for (int i = 0; i < 4; ++i) {
                    float2 v = acc[i][j];
                    v.x += bz * bias_s[eg * 4 + i];
                    dst[(eg * 4 + i) * 64 + x] = v;
                }
            }
        }
        __syncthreads();
    }

    {
        int xg = tid & 15, yg = tid >> 4;
        float2 acc[4][4];
#pragma unroll
        for (int i = 0; i < 4; ++i)
#pragma unroll
            for (int j = 0; j < 4; ++j) acc[i][j] = make_float2(0.f, 0.f);
        for (int e = 0; e < 64; ++e) {
            float2 qv[4], kv[4];
#pragma unroll
            for (int i = 0; i < 4; ++i) qv[i] = Qf[e * 64 + xg + 16 * i];
#pragma unroll
            for (int j = 0; j < 4; ++j) kv[j] = Kf[e * 64 + yg * 4 + j];
#pragma unroll
            for (int i = 0; i < 4; ++i)
#pragma unroll
                for (int j = 0; j < 4; ++j) {
                    acc[i][j].x += qv[i].x * kv[j].x - qv[i].y * kv[j].y;
                    acc[i][j].y += qv[i].x * kv[j].y + qv[i].y * kv[j].x;
                }
        }
#pragma unroll
        for (int i = 0; i < 4; ++i)
#pragma unroll
            for (int j = 0; j < 4; ++j)
                bufA[(yg * 4 + j) * 64 + xg + 16 * i] =
                    make_float2(tanhf(acc[i][j].x), tanhf(acc[i][j].y));
    }
    __syncthreads();

    {
        int xg = tid & 15, eg = tid >> 4;
        float2 acc[4][4];
#pragma unroll
        for (int i = 0; i < 4; ++i)
#pragma unroll
            for (int j = 0; j < 4; ++j) acc[i][j] = make_float2(0.f, 0.f);
        for (int y = 0; y < 64; ++y) {
            float2 kv[4], tv[4];
#pragma unroll
            for (int i = 0; i < 4; ++i) kv[i] = Kf[(eg * 4 + i) * 64 + y];
#pragma unroll
            for (int j = 0; j < 4; ++j) tv[j] = bufA[y * 64 + xg + 16 * j];
#pragma unroll
            for (int i = 0; i < 4; ++i)
#pragma unroll
                for (int j = 0; j < 4; ++j) {
                    acc[i][j].x += tv[j].x * kv[i].x - tv[j].y * kv[i].y;
                    acc[i][j].y += tv[j].x * kv[i].y + tv[j].y * kv[i].x;
                }
        }
        float2* Ud = U + gb;
#pragma unroll
        for (int i = 0; i < 4; ++i)
#pragma unroll
            for (int j = 0; j < 4; ++j)
                Ud[(eg * 4 + i) * 64 + xg + 16 * j] = acc[i][j];
    }
}

// ---------------------------------------------------------------------------
// Per (h,x): X[b,o] = sum_e U[b,e] wc[e,o]; fold irfft scales; A[b][h][o][x]=(P,Q).
__global__ __launch_bounds__(128) void k_apply_w(
    const float2* __restrict__ U, const float2* __restrict__ wc,
    const int* __restrict__ iq, float2* __restrict__ A)
{
    int x = blockIdx.x, h = blockIdx.y;
    int tid = threadIdx.x;
    __shared__ float2 wl[4096];
    __shared__ float2 ul[16][65];
    const float4* wsrc = (const float4*)(wc + (size_t)(h * 64 + x) * 4096);
#pragma unroll
    for (int j = 0; j < 16; ++j)
        ((float4*)wl)[tid + 128 * j] = wsrc[tid + 128 * j];
#pragma unroll
    for (int j = 0; j < 8; ++j) {
        int idx = tid + 128 * j;
        int bb = idx >> 6, e = idx & 63;
        ul[bb][e] = U[((size_t)(bb * 8 + h) * 64 + e) * 64 + x];
    }
    __syncthreads();
    int bb = tid >> 3, og = tid & 7;
    float2 acc[8];
#pragma unroll
    for (int j = 0; j < 8; ++j) acc[j] = make_float2(0.f, 0.f);
    for (int e = 0; e < 64; ++e) {
        float2 u = ul[bb][e];
#pragma unroll
        for (int j = 0; j < 8; ++j) {
            float2 wv = wl[e * 64 + og + 8 * j];
            acc[j].x += u.x * wv.x - u.y * wv.y;
            acc[j].y += u.x * wv.y + u.y * wv.x;
        }
    }
    int f = iq[x];
    bool dc = (f == 0) || (2 * f == Lseq);
    float cm = (dc ? 1.0f : 2.0f) * (1.0f / (2048.0f * 262144.0f));
    float2* Ad = A + (size_t)(bb * 8 + h) * 4096;
#pragma unroll
    for (int j = 0; j < 8; ++j) {
        int o = og + 8 * j;
        Ad[o * 64 + x] = make_float2(cm * acc[j].x, dc ? 0.0f : -cm * acc[j].y);
    }
}

// ---------------------------------------------------------------------------
// Radix-4 inverse: out[t'+512j] from U_r/V_r class sums.
// grid (tt:8, h, b), 512 thr: wave = o-slice of 8 (A reads wave-uniform),
// lane = t'. tw tile XOR-swizzled by row (2-way max conflicts).
__global__ __launch_bounds__(512) void k_irfft(
    const float2* __restrict__ A, const float* __restrict__ tw,
    float* __restrict__ out)
{
    int tt = blockIdx.x, h = blockIdx.y, b = blockIdx.z;
    int t0 = tt * 64;
    int tid = threadIdx.x;
    __shared__ float2 A_s[4096];        // [o][x] (P,Q)
    __shared__ float  tw_s[64][128];    // rows t', XOR-swizzled float4s
    const float4* asrc = (const float4*)(A + (size_t)(b * 8 + h) * 4096);
#pragma unroll
    for (int j = 0; j < 4; ++j)
        ((float4*)A_s)[tid + 512 * j] = asrc[tid + 512 * j];
    {
        int row = tid >> 3, c4b = (tid & 7) * 4;
        const float4* s = (const float4*)(tw + (size_t)(t0 + row) * 128);
        float4* drow = (float4*)&tw_s[row][0];
#pragma unroll
        for (int kk = 0; kk < 4; ++kk) {
            int c4 = c4b + kk;
            drow[c4 ^ (row & 31)] = s[c4];
        }
    }
    __syncthreads();
    int tl = tid & 63, ow = tid >> 6;    // o = ow*8 + i
    float U0[8], U1[8], V1[8], U2[8], U3[8], V3[8];
#pragma unroll
    for (int i = 0; i < 8; ++i) { U0[i]=U1[i]=V1[i]=U2[i]=U3[i]=V3[i]=0.f; }
    const float4* trow = (const float4*)&tw_s[tl][0];
    int sw = tl & 31;
#pragma unroll
    for (int g = 0; g < 16; ++g) {
        float4 w0 = trow[(2 * g) ^ sw];       // c(4g),s(4g),c(4g+1),s(4g+1)
        float4 w1 = trow[(2 * g + 1) ^ sw];   // c(4g+2),s(4g+2),c(4g+3),s(4g+3)
#pragma unroll
        for (int i = 0; i < 8; ++i) {
            const float4* ap = (const float4*)&A_s[(ow * 8 + i) * 64 + 4 * g];
            float4 a0 = ap[0];   // P0,Q0,P1,Q1
            float4 a1 = ap[1];   // P2,Q2,P3,Q3
            U0[i] += a0.x * w0.x + a0.y * w0.y;
            U1[i] += a0.z * w0.z + a0.w * w0.w;
            V1[i] += a0.w * w0.z - a0.z * w0.w;
            U2[i] += a1.x * w1.x + a1.y * w1.y;
            U3[i] += a1.z * w1.z + a1.w * w1.w;
            V3[i] += a1.w * w1.z - a1.z * w1.w;
        }
    }
    float* op = out + ((size_t)(b * 8 + h) * 64 + ow * 8) * Lseq + t0 + tl;
#pragma unroll
    for (int i = 0; i < 8; ++i) {
        float u0 = U0[i], u1 = U1[i], v1 = V1[i], u2 = U2[i], u3 = U3[i], v3 = V3[i];
        op[(size_t)i * Lseq +    0] = u0 + u1 + u2 + u3;
        op[(size_t)i * Lseq +  512] = u0 + v1 - u2 - v3;
        op[(size_t)i * Lseq + 1024] = u0 - u1 + u2 - u3;
        op[(size_t)i * Lseq + 1536] = u0 - v1 - u2 + v3;
    }
}

// ---------------------------------------------------------------------------
extern "C" void kernel_launch(void* const* d_in, const int* in_sizes, int n_in,
                              void* d_out, int out_size, void* d_ws, size_t ws_size,
                              hipStream_t stream)
{
    const float* q    = (const float*)d_in[0];
    const float* k    = (const float*)d_in[1];
    const float* wq_w = (const float*)d_in[3];
    const float* wq_b = (const float*)d_in[4];
    const float* wk_w = (const float*)d_in[5];
    const float* wk_b = (const float*)d_in[6];
    const float* w1   = (const float*)d_in[9];
    const float* w2   = (const float*)d_in[10];
    const int*   iq   = (const int*)d_in[11];
    const int*   ikv  = (const int*)d_in[12];
    float* out = (float*)d_out;

    char* ws = (char*)d_ws;
    float2* twq = (float2*)(ws + OFF_TWQ);
    float2* twk = (float2*)(ws + OFF_TWK);
    float2* Gq  = (float2*)(ws + OFF_GQ);
    float2* Gk  = (float2*)(ws + OFF_GK);
    float2* Uw  = (float2*)(ws + OFF_U);
    float2* Aw  = (float2*)(ws + OFF_A);
    float2* wc  = (float2*)(ws + OFF_WC);

    k_twiddle<<<128, 256, 0, stream>>>(iq, ikv, twq, twk);
    k_dft<<<dim3(16, 8, 2), 512, 0, stream>>>(q, k, (const float*)twq,
                                              (const float*)twk, Gq, Gk);
    k_core<<<dim3(16, 8), 256, 0, stream>>>(Gq, Gk, wq_w, wq_b, wk_w, wk_b,
                                            iq, ikv, Uw);
    k_wtrans<<<dim3(8, 64), 256, 0, stream>>>(w1, w2, wc);
    k_apply_w<<<dim3(64, 8), 128, 0, stream>>>(Uw, wc, iq, Aw);
    k_irfft<<<dim3(8, 8, 16), 512, 0, stream>>>(Aw, (const float*)twq, out);
}

// Round 6
// 722.111 us; speedup vs baseline: 1.0935x; 1.0275x over previous
//
#include <hip/hip_runtime.h>
#include <math.h>

#define Lseq 2048
// B=16, H=8, E=64, O=64, MODES=64
// Radix-4 DIF decomposition: all selected freqs f < 64, f = 4g + r.
// t = t' + 512 j, t' in [0,512):  e^{-2pi i f t/2048} = tw(t',f) * (-i)^{r j}
// y0 = x0+x1+x2+x3 (r=0), y2 = x0-x1+x2-x3 (r=2), y1 = p - i q, y3 = p + i q
// with p = x0-x2, q = x1-x3  (x_j = x[t'+512 j]).

// ---------------- workspace layout (bytes) ----------------
// twq [512][64] float2  256 KB   twiddles (cos, +sin) at freq index_q
// twk [512][64] float2  256 KB   twiddles at freq index_kv
// Gq  [16][8][64][64]c    4 MB
// Gk                      4 MB
// U                       4 MB
// A                       4 MB
// wc  [8][64][64][64] f2 16 MB
#define OFF_TWQ 0u
#define OFF_TWK (256u << 10)
#define OFF_GQ  (1u << 20)
#define OFF_GK  (5u << 20)
#define OFF_U   (9u << 20)
#define OFF_A   (13u << 20)
#define OFF_WC  (17u << 20)

// ---------------------------------------------------------------------------
__global__ __launch_bounds__(256) void k_twiddle(
    const int* __restrict__ iq, const int* __restrict__ ikv,
    float2* __restrict__ twq, float2* __restrict__ twk)
{
    int idx = blockIdx.x * 256 + threadIdx.x;   // 0 .. 512*64-1
    int t = idx >> 6;
    int m = idx & 63;
    const float w = 6.2831853071795864769f / (float)Lseq;
    float s, c;
    int ph = (t * iq[m]) & (Lseq - 1);
    sincosf(w * (float)ph, &s, &c);
    twq[idx] = make_float2(c, s);
    ph = (t * ikv[m]) & (Lseq - 1);
    sincosf(w * (float)ph, &s, &c);
    twk[idx] = make_float2(c, s);
}

// ---------------------------------------------------------------------------
// Transpose weights to wc[h][x][e][o]
__global__ __launch_bounds__(256) void k_wtrans(
    const float* __restrict__ w1, const float* __restrict__ w2,
    float2* __restrict__ wc)
{
    int h = blockIdx.x, e = blockIdx.y;
    const float* p1 = w1 + (((size_t)h * 64 + e) * 64) * 64;  // [o][x]
    const float* p2 = w2 + (((size_t)h * 64 + e) * 64) * 64;
    __shared__ float s1[64][65];
    __shared__ float s2[64][65];
    int tid = threadIdx.x;
    for (int i = tid; i < 1024; i += 256) {
        int o = i >> 4, xc = (i & 15) * 4;
        float4 a = *(const float4*)(p1 + o * 64 + xc);
        s1[o][xc] = a.x; s1[o][xc + 1] = a.y; s1[o][xc + 2] = a.z; s1[o][xc + 3] = a.w;
        float4 b = *(const float4*)(p2 + o * 64 + xc);
        s2[o][xc] = b.x; s2[o][xc + 1] = b.y; s2[o][xc + 2] = b.z; s2[o][xc + 3] = b.w;
    }
    __syncthreads();
    float2* dst = wc + ((size_t)h * 64) * 4096 + (size_t)e * 64;
    for (int i = tid; i < 4096; i += 256) {
        int x = i >> 6, o = i & 63;
        dst[(size_t)x * 4096 + o] = make_float2(s1[o][x], s2[o][x]);
    }
}

// ---------------------------------------------------------------------------
// Radix-4 partial DFT, sized for the backend's 128-VGPR budget:
//  - v2/v5 lesson: with 512-thread blocks the allocator pins VGPR_Count=128
//    (4 waves/EU target) regardless of LDS occupancy; a 96-acc thread (~200
//    live regs) spills ~70 regs -> 1.8 GB scratch, 10% VALUBusy, 467-515 us.
//    Fix: 48 accumulators/thread -> ~120 live regs -> fits 128, no spill.
//  - grid (b, h, z): one block = full 512 t' for one signal. No split-K.
//  - 512 threads = 2 subs x 256; sub s owns t' in [256s, 256s+256),
//    16 rounds of 16 t'.
//  - compute thread (eg,g): e-tile 4 (e = 4eg..4eg+3), mode-quad 4g..4g+3,
//    48 fp32 accumulators; twiddles live in registers and rotate by
//    delta_f = tw-row[t=1] each t' step, re-initialized exactly from the
//    table each round (max 15 rotations -> ~8 ulp drift, << fp32 sum noise;
//    v2 verified the 7-rotation variant bit-comparable to table lookups).
//  - y_s double-buffered (2 x 32 KB): ONE barrier per round; next-round
//    global x loads + twiddle row issued right after the barrier so HBM
//    latency hides under the 16-tt compute block.
//  - 2-sub reduce in LDS (aliases y_s), direct write to Gq/Gk.
__global__ __launch_bounds__(512) void k_dft(
    const float* __restrict__ q, const float* __restrict__ k,
    const float* __restrict__ twq, const float* __restrict__ twk,
    float2* __restrict__ Gq, float2* __restrict__ Gk)
{
    int b = blockIdx.x, h = blockIdx.y, z = blockIdx.z;
    const float* src = z ? k : q;
    const float* tws = z ? twk : twq;

    __shared__ float y_s[2][2][16][4][64];   // 64 KB: [buf][sub][t'][comp][e]

    int tid = threadIdx.x;
    int sub = tid >> 8;            // t' half (wave-uniform: waves 0-3 / 4-7)
    int st  = tid & 255;
    int tl  = st >> 4;             // staging row 0..15
    int e4q = st & 15;             // staging e-quad
    int eg  = st >> 4;             // compute e-group (4 e)
    int g   = st & 15;             // compute mode-quad (modes 4g..4g+3)
    int tbase = sub * 256;

    const float* xbase = src + ((size_t)b * Lseq) * 512 + h * 64;
    const float* xrow0 = xbase + (size_t)(tbase + tl) * 512 + e4q * 4;

    // per-step rotation constants: delta_f = tw(t=1, f), exact from table
    const float* trow1 = tws + 128 + g * 8;
    float4 d0 = *(const float4*)(trow1);
    float4 d1 = *(const float4*)(trow1 + 4);
    float dc[4], dsn[4];
    dc[0] = d0.x; dsn[0] = d0.y; dc[1] = d0.z; dsn[1] = d0.w;
    dc[2] = d1.x; dsn[2] = d1.y; dc[3] = d1.z; dsn[3] = d1.w;

    float a[4][12];
#pragma unroll
    for (int i = 0; i < 4; ++i)
#pragma unroll
        for (int j = 0; j < 12; ++j) a[i][j] = 0.f;

    // prologue: round-0 x loads + twiddle row (exact at t' = tbase)
    float4 c0 = *(const float4*)(xrow0);
    float4 c1 = *(const float4*)(xrow0 + 262144);
    float4 c2 = *(const float4*)(xrow0 + 524288);
    float4 c3 = *(const float4*)(xrow0 + 786432);
    const float* trow = tws + (size_t)tbase * 128 + g * 8;
    float4 tA = *(const float4*)(trow);
    float4 tB = *(const float4*)(trow + 4);
    float4 n0, n1, n2, n3, uA, uB;

    for (int rnd = 0; rnd < 16; ++rnd) {
        int buf = rnd & 1;
        {   // butterfly + stage into y_s[buf]
            float4 sa, sb, y0, y2, pp, qq;
            sa.x = c0.x + c2.x; sa.y = c0.y + c2.y; sa.z = c0.z + c2.z; sa.w = c0.w + c2.w;
            sb.x = c1.x + c3.x; sb.y = c1.y + c3.y; sb.z = c1.z + c3.z; sb.w = c1.w + c3.w;
            y0.x = sa.x + sb.x; y0.y = sa.y + sb.y; y0.z = sa.z + sb.z; y0.w = sa.w + sb.w;
            y2.x = sa.x - sb.x; y2.y = sa.y - sb.y; y2.z = sa.z - sb.z; y2.w = sa.w - sb.w;
            pp.x = c0.x - c2.x; pp.y = c0.y - c2.y; pp.z = c0.z - c2.z; pp.w = c0.w - c2.w;
            qq.x = c1.x - c3.x; qq.y = c1.y - c3.y; qq.z = c1.z - c3.z; qq.w = c1.w - c3.w;
            *(float4*)&y_s[buf][sub][tl][0][e4q * 4] = y0;
            *(float4*)&y_s[buf][sub][tl][1][e4q * 4] = y2;
            *(float4*)&y_s[buf][sub][tl][2][e4q * 4] = pp;
            *(float4*)&y_s[buf][sub][tl][3][e4q * 4] = qq;
        }
        __syncthreads();
        if (rnd < 15) {   // prefetch next round: latency hides under compute
            const float* p = xrow0 + (size_t)(rnd + 1) * (16 * 512);
            n0 = *(const float4*)(p);
            n1 = *(const float4*)(p + 262144);
            n2 = *(const float4*)(p + 524288);
            n3 = *(const float4*)(p + 786432);
            const float* tr = tws + (size_t)(tbase + (rnd + 1) * 16) * 128 + g * 8;
            uA = *(const float4*)(tr);
            uB = *(const float4*)(tr + 4);
        }
        // twiddle registers for this round (exact at t' = tbase + rnd*16)
        float wc_[4], ws_[4];
        wc_[0] = tA.x; ws_[0] = tA.y; wc_[1] = tA.z; ws_[1] = tA.w;
        wc_[2] = tB.x; ws_[2] = tB.y; wc_[3] = tB.z; ws_[3] = tB.w;
#pragma unroll
        for (int tt = 0; tt < 16; ++tt) {
            float4 Y0 = *(float4*)&y_s[buf][sub][tt][0][eg * 4];
            float4 Y2 = *(float4*)&y_s[buf][sub][tt][1][eg * 4];
            float4 Pv = *(float4*)&y_s[buf][sub][tt][2][eg * 4];
            float4 Qv = *(float4*)&y_s[buf][sub][tt][3][eg * 4];
            const float* y0a = (const float*)&Y0;
            const float* y2a = (const float*)&Y2;
            const float* pa  = (const float*)&Pv;
            const float* qa  = (const float*)&Qv;
#pragma unroll
            for (int i = 0; i < 4; ++i) {
                a[i][0]  += y0a[i] * wc_[0];  a[i][1]  += y0a[i] * ws_[0];
                a[i][2]  += y2a[i] * wc_[2];  a[i][3]  += y2a[i] * ws_[2];
                a[i][4]  += pa[i]  * wc_[1];  a[i][5]  += qa[i]  * ws_[1];
                a[i][6]  += pa[i]  * ws_[1];  a[i][7]  += qa[i]  * wc_[1];
                a[i][8]  += pa[i]  * wc_[3];  a[i][9]  += qa[i]  * ws_[3];
                a[i][10] += pa[i]  * ws_[3];  a[i][11] += qa[i]  * wc_[3];
            }
            if (tt < 15) {   // rotate the 4 twiddles one t' step
#pragma unroll
                for (int m = 0; m < 4; ++m) {
                    float c = wc_[m], s = ws_[m];
                    wc_[m] = c * dc[m] - s * dsn[m];
                    ws_[m] = s * dc[m] + c * dsn[m];
                }
            }
        }
        if (rnd < 15) {
            c0 = n0; c1 = n1; c2 = n2; c3 = n3;
            tA = uA; tB = uB;
        }
    }

    __syncthreads();   // y_s free for reduce

    // combine accumulators to complex G: per thread 4e x 4 modes = 8 float4
    float4 gvf[8];
#pragma unroll
    for (int i = 0; i < 4; ++i) {
        gvf[i * 2 + 0] = make_float4(a[i][0], -a[i][1], a[i][4] - a[i][5], -(a[i][6] + a[i][7]));
        gvf[i * 2 + 1] = make_float4(a[i][2], -a[i][3], a[i][8] + a[i][9], a[i][11] - a[i][10]);
    }

    // 2-sub reduce in LDS (XOR-swizzled float4 slots for full-rate banks)
    float4* red = (float4*)y_s;              // 256 threads x 8 float4 = 32 KB
    int rbase = st * 8;
    int sx = st & 7;
    if (sub == 1) {
#pragma unroll
        for (int j = 0; j < 8; ++j) red[rbase + (j ^ sx)] = gvf[j];
    }
    __syncthreads();
    if (sub == 0) {
#pragma unroll
        for (int j = 0; j < 8; ++j) {
            float4 r = red[rbase + (j ^ sx)];
            gvf[j].x += r.x; gvf[j].y += r.y; gvf[j].z += r.z; gvf[j].w += r.w;
        }
        float4* Gd4 = (float4*)((z ? Gk : Gq) + (size_t)(b * 8 + h) * 4096);
#pragma unroll
        for (int i = 0; i < 4; ++i) {
            Gd4[(eg * 4 + i) * 32 + 2 * g + 0] = gvf[i * 2 + 0];
            Gd4[(eg * 4 + i) * 32 + 2 * g + 1] = gvf[i * 2 + 1];
        }
    }
}

// ---------------------------------------------------------------------------
// Per (b,h): freq-domain projection of q,k; S = Q^T K; tanh; U = T K.
__global__ __launch_bounds__(256) void k_core(
    const float2* __restrict__ Gq, const float2* __restrict__ Gk,
    const float* __restrict__ wqw, const float* __restrict__ wqb,
    const float* __restrict__ wkw, const float* __restrict__ wkb,
    const int* __restrict__ iq, const int* __restrict__ ikv,
    float2* __restrict__ U)
{
    int b = blockIdx.x, h = blockIdx.y;
    int tid = threadIdx.x;
    __shared__ float2 bufA[4096];
    __shared__ float2 Qf[4096];
    __shared__ float2 Kf[4096];
    __shared__ float  Wm[4096];
    __shared__ float  bias_s[64];
    __shared__ int    idx_s[64];

    size_t gb = (size_t)(b * 8 + h) * 4096;

    for (int z = 0; z < 2; ++z) {
        const float* Wsrc = z ? wkw : wqw;
        const float* bsrc = z ? wkb : wqb;
        const int*   isrc = z ? ikv : iq;
        const float2* Gsrc = (z ? Gk : Gq) + gb;
        float2* dst = z ? Kf : Qf;
        if (tid < 64) { bias_s[tid] = bsrc[tid]; idx_s[tid] = isrc[tid]; }
#pragma unroll
        for (int j = 0; j < 4; ++j)
            ((float4*)Wm)[tid + 256 * j] = ((const float4*)Wsrc)[tid + 256 * j];
#pragma unroll
        for (int j = 0; j < 8; ++j)
            ((float4*)bufA)[tid + 256 * j] = ((const float4*)Gsrc)[tid + 256 * j];
        __syncthreads();
        {
            int eg = tid >> 4, xg = tid & 15;
            float2 acc[4][4];
#pragma unroll
            for (int i = 0; i < 4; ++i)
#pragma unroll
                for (int j = 0; j < 4; ++j) acc[i][j] = make_float2(0.f, 0.f);
            for (int ep = 0; ep < 64; ++ep) {
                float wv[4]; float2 gvv[4];
#pragma unroll
                for (int i = 0; i < 4; ++i) wv[i] = Wm[(eg * 4 + i) * 64 + ep];
#pragma unroll
                for (int j = 0; j < 4; ++j) gvv[j] = bufA[ep * 64 + xg + 16 * j];
#pragma unroll
                for (int i = 0; i < 4; ++i)
#pragma unroll
                    for (int j = 0; j < 4; ++j) {
                        acc[i][j].x += wv[i] * gvv[j].x;
                        acc[i][j].y += wv[i] * gvv[j].y;
                    }
            }
#pragma unroll
            for (int j = 0; j < 4; ++j) {
                int x = xg + 16 * j;
                float bz = (idx_s[x] == 0) ? 2048.0f : 0.0f;
#pragma unroll
                for (int i = 0; i < 4; ++i) {
                    float2 v = acc[i][j];
                    v.x += bz * bias_s[eg * 4 + i];
                    dst[(eg * 4 + i) * 64 + x] = v;
                }
            }
        }
        __syncthreads();
    }

    {
        int xg = tid & 15, yg = tid >> 4;
        float2 acc[4][4];
#pragma unroll
        for (int i = 0; i < 4; ++i)
#pragma unroll
            for (int j = 0; j < 4; ++j) acc[i][j] = make_float2(0.f, 0.f);
        for (int e = 0; e < 64; ++e) {
            float2 qv[4], kv[4];
#pragma unroll
            for (int i = 0; i < 4; ++i) qv[i] = Qf[e * 64 + xg + 16 * i];
#pragma unroll
            for (int j = 0; j < 4; ++j) kv[j] = Kf[e * 64 + yg * 4 + j];
#pragma unroll
            for (int i = 0; i < 4; ++i)
#pragma unroll
                for (int j = 0; j < 4; ++j) {
                    acc[i][j].x += qv[i].x * kv[j].x - qv[i].y * kv[j].y;
                    acc[i][j].y += qv[i].x * kv[j].y + qv[i].y * kv[j].x;
                }
        }
#pragma unroll
        for (int i = 0; i < 4; ++i)
#pragma unroll
            for (int j = 0; j < 4; ++j)
                bufA[(yg * 4 + j) * 64 + xg + 16 * i] =
                    make_float2(tanhf(acc[i][j].x), tanhf(acc[i][j].y));
    }
    __syncthreads();

    {
        int xg = tid & 15, eg = tid >> 4;
        float2 acc[4][4];
#pragma unroll
        for (int i = 0; i < 4; ++i)
#pragma unroll
            for (int j = 0; j < 4; ++j) acc[i][j] = make_float2(0.f, 0.f);
        for (int y = 0; y < 64; ++y) {
            float2 kv[4], tv[4];
#pragma unroll
            for (int i = 0; i < 4; ++i) kv[i] = Kf[(eg * 4 + i) * 64 + y];
#pragma unroll
            for (int j = 0; j < 4; ++j) tv[j] = bufA[y * 64 + xg + 16 * j];
#pragma unroll
            for (int i = 0; i < 4; ++i)
#pragma unroll
                for (int j = 0; j < 4; ++j) {
                    acc[i][j].x += tv[j].x * kv[i].x - tv[j].y * kv[i].y;
                    acc[i][j].y += tv[j].x * kv[i].y + tv[j].y * kv[i].x;
                }
        }
        float2* Ud = U + gb;
#pragma unroll
        for (int i = 0; i < 4; ++i)
#pragma unroll
            for (int j = 0; j < 4; ++j)
                Ud[(eg * 4 + i) * 64 + xg + 16 * j] = acc[i][j];
    }
}

// ---------------------------------------------------------------------------
// Per (h,x): X[b,o] = sum_e U[b,e] wc[e,o]; fold irfft scales; A[b][h][o][x]=(P,Q).
__global__ __launch_bounds__(128) void k_apply_w(
    const float2* __restrict__ U, const float2* __restrict__ wc,
    const int* __restrict__ iq, float2* __restrict__ A)
{
    int x = blockIdx.x, h = blockIdx.y;
    int tid = threadIdx.x;
    __shared__ float2 wl[4096];
    __shared__ float2 ul[16][65];
    const float4* wsrc = (const float4*)(wc + (size_t)(h * 64 + x) * 4096);
#pragma unroll
    for (int j = 0; j < 16; ++j)
        ((float4*)wl)[tid + 128 * j] = wsrc[tid + 128 * j];
#pragma unroll
    for (int j = 0; j < 8; ++j) {
        int idx = tid + 128 * j;
        int bb = idx >> 6, e = idx & 63;
        ul[bb][e] = U[((size_t)(bb * 8 + h) * 64 + e) * 64 + x];
    }
    __syncthreads();
    int bb = tid >> 3, og = tid & 7;
    float2 acc[8];
#pragma unroll
    for (int j = 0; j < 8; ++j) acc[j] = make_float2(0.f, 0.f);
    for (int e = 0; e < 64; ++e) {
        float2 u = ul[bb][e];
#pragma unroll
        for (int j = 0; j < 8; ++j) {
            float2 wv = wl[e * 64 + og + 8 * j];
            acc[j].x += u.x * wv.x - u.y * wv.y;
            acc[j].y += u.x * wv.y + u.y * wv.x;
        }
    }
    int f = iq[x];
    bool dc = (f == 0) || (2 * f == Lseq);
    float cm = (dc ? 1.0f : 2.0f) * (1.0f / (2048.0f * 262144.0f));
    float2* Ad = A + (size_t)(bb * 8 + h) * 4096;
#pragma unroll
    for (int j = 0; j < 8; ++j) {
        int o = og + 8 * j;
        Ad[o * 64 + x] = make_float2(cm * acc[j].x, dc ? 0.0f : -cm * acc[j].y);
    }
}

// ---------------------------------------------------------------------------
// Radix-4 inverse: out[t'+512j] from U_r/V_r class sums.
// grid (tt:8, h, b), 512 thr: wave = o-slice of 8 (A reads wave-uniform),
// lane = t'. tw tile XOR-swizzled by row (2-way max conflicts).
__global__ __launch_bounds__(512) void k_irfft(
    const float2* __restrict__ A, const float* __restrict__ tw,
    float* __restrict__ out)
{
    int tt = blockIdx.x, h = blockIdx.y, b = blockIdx.z;
    int t0 = tt * 64;
    int tid = threadIdx.x;
    __shared__ float2 A_s[4096];        // [o][x] (P,Q)
    __shared__ float  tw_s[64][128];    // rows t', XOR-swizzled float4s
    const float4* asrc = (const float4*)(A + (size_t)(b * 8 + h) * 4096);
#pragma unroll
    for (int j = 0; j < 4; ++j)
        ((float4*)A_s)[tid + 512 * j] = asrc[tid + 512 * j];
    {
        int row = tid >> 3, c4b = (tid & 7) * 4;
        const float4* s = (const float4*)(tw + (size_t)(t0 + row) * 128);
        float4* drow = (float4*)&tw_s[row][0];
#pragma unroll
        for (int kk = 0; kk < 4; ++kk) {
            int c4 = c4b + kk;
            drow[c4 ^ (row & 31)] = s[c4];
        }
    }
    __syncthreads();
    int tl = tid & 63, ow = tid >> 6;    // o = ow*8 + i
    float U0[8], U1[8], V1[8], U2[8], U3[8], V3[8];
#pragma unroll
    for (int i = 0; i < 8; ++i) { U0[i]=U1[i]=V1[i]=U2[i]=U3[i]=V3[i]=0.f; }
    const float4* trow = (const float4*)&tw_s[tl][0];
    int sw = tl & 31;
#pragma unroll
    for (int g = 0; g < 16; ++g) {
        float4 w0 = trow[(2 * g) ^ sw];       // c(4g),s(4g),c(4g+1),s(4g+1)
        float4 w1 = trow[(2 * g + 1) ^ sw];   // c(4g+2),s(4g+2),c(4g+3),s(4g+3)
#pragma unroll
        for (int i = 0; i < 8; ++i) {
            const float4* ap = (const float4*)&A_s[(ow * 8 + i) * 64 + 4 * g];
            float4 a0 = ap[0];   // P0,Q0,P1,Q1
            float4 a1 = ap[1];   // P2,Q2,P3,Q3
            U0[i] += a0.x * w0.x + a0.y * w0.y;
            U1[i] += a0.z * w0.z + a0.w * w0.w;
            V1[i] += a0.w * w0.z - a0.z * w0.w;
            U2[i] += a1.x * w1.x + a1.y * w1.y;
            U3[i] += a1.z * w1.z + a1.w * w1.w;
            V3[i] += a1.w * w1.z - a1.z * w1.w;
        }
    }
    float* op = out + ((size_t)(b * 8 + h) * 64 + ow * 8) * Lseq + t0 + tl;
#pragma unroll
    for (int i = 0; i < 8; ++i) {
        float u0 = U0[i], u1 = U1[i], v1 = V1[i], u2 = U2[i], u3 = U3[i], v3 = V3[i];
        op[(size_t)i * Lseq +    0] = u0 + u1 + u2 + u3;
        op[(size_t)i * Lseq +  512] = u0 + v1 - u2 - v3;
        op[(size_t)i * Lseq + 1024] = u0 - u1 + u2 - u3;
        op[(size_t)i * Lseq + 1536] = u0 - v1 - u2 + v3;
    }
}

// ---------------------------------------------------------------------------
extern "C" void kernel_launch(void* const* d_in, const int* in_sizes, int n_in,
                              void* d_out, int out_size, void* d_ws, size_t ws_size,
                              hipStream_t stream)
{
    const float* q    = (const float*)d_in[0];
    const float* k    = (const float*)d_in[1];
    const float* wq_w = (const float*)d_in[3];
    const float* wq_b = (const float*)d_in[4];
    const float* wk_w = (const float*)d_in[5];
    const float* wk_b = (const float*)d_in[6];
    const float* w1   = (const float*)d_in[9];
    const float* w2   = (const float*)d_in[10];
    const int*   iq   = (const int*)d_in[11];
    const int*   ikv  = (const int*)d_in[12];
    float* out = (float*)d_out;

    char* ws = (char*)d_ws;
    float2* twq = (float2*)(ws + OFF_TWQ);
    float2* twk = (float2*)(ws + OFF_TWK);
    float2* Gq  = (float2*)(ws + OFF_GQ);
    float2* Gk  = (float2*)(ws + OFF_GK);
    float2* Uw  = (float2*)(ws + OFF_U);
    float2* Aw  = (float2*)(ws + OFF_A);
    float2* wc  = (float2*)(ws + OFF_WC);

    k_twiddle<<<128, 256, 0, stream>>>(iq, ikv, twq, twk);
    k_dft<<<dim3(16, 8, 2), 512, 0, stream>>>(q, k, (const float*)twq,
                                              (const float*)twk, Gq, Gk);
    k_core<<<dim3(16, 8), 256, 0, stream>>>(Gq, Gk, wq_w, wq_b, wk_w, wk_b,
                                            iq, ikv, Uw);
    k_wtrans<<<dim3(8, 64), 256, 0, stream>>>(w1, w2, wc);
    k_apply_w<<<dim3(64, 8), 128, 0, stream>>>(Uw, wc, iq, Aw);
    k_irfft<<<dim3(8, 8, 16), 512, 0, stream>>>(Aw, (const float*)twq, out);
}

// Round 7
// 392.125 us; speedup vs baseline: 2.0138x; 1.8415x over previous
//
#include <hip/hip_runtime.h>
#include <math.h>

#define Lseq 2048
// B=16, H=8, E=64, O=64, MODES=64
// Radix-4 DIF decomposition: all selected freqs f < 64, f = 4g + r.
// t = t' + 512 j, t' in [0,512):  e^{-2pi i f t/2048} = tw(t',f) * (-i)^{r j}
// y0 = x0+x1+x2+x3 (r=0), y2 = x0-x1+x2-x3 (r=2), y1 = p - i q, y3 = p + i q
// with p = x0-x2, q = x1-x3  (x_j = x[t'+512 j]).

// ---------------- workspace layout (bytes) ----------------
// twq [512][64] float2  256 KB   twiddles (cos, +sin) at freq index_q
// twk [512][64] float2  256 KB   twiddles at freq index_kv
// Gq  [16][8][64][64]c    4 MB
// Gk                      4 MB
// U                       4 MB
// A                       4 MB
// wc  [8][64][64][64] f2 16 MB
#define OFF_TWQ 0u
#define OFF_TWK (256u << 10)
#define OFF_GQ  (1u << 20)
#define OFF_GK  (5u << 20)
#define OFF_U   (9u << 20)
#define OFF_A   (13u << 20)
#define OFF_WC  (17u << 20)

// ---------------------------------------------------------------------------
__global__ __launch_bounds__(256) void k_twiddle(
    const int* __restrict__ iq, const int* __restrict__ ikv,
    float2* __restrict__ twq, float2* __restrict__ twk)
{
    int idx = blockIdx.x * 256 + threadIdx.x;   // 0 .. 512*64-1
    int t = idx >> 6;
    int m = idx & 63;
    const float w = 6.2831853071795864769f / (float)Lseq;
    float s, c;
    int ph = (t * iq[m]) & (Lseq - 1);
    sincosf(w * (float)ph, &s, &c);
    twq[idx] = make_float2(c, s);
    ph = (t * ikv[m]) & (Lseq - 1);
    sincosf(w * (float)ph, &s, &c);
    twk[idx] = make_float2(c, s);
}

// ---------------------------------------------------------------------------
// Transpose weights to wc[h][x][e][o]
__global__ __launch_bounds__(256) void k_wtrans(
    const float* __restrict__ w1, const float* __restrict__ w2,
    float2* __restrict__ wc)
{
    int h = blockIdx.x, e = blockIdx.y;
    const float* p1 = w1 + (((size_t)h * 64 + e) * 64) * 64;  // [o][x]
    const float* p2 = w2 + (((size_t)h * 64 + e) * 64) * 64;
    __shared__ float s1[64][65];
    __shared__ float s2[64][65];
    int tid = threadIdx.x;
    for (int i = tid; i < 1024; i += 256) {
        int o = i >> 4, xc = (i & 15) * 4;
        float4 a = *(const float4*)(p1 + o * 64 + xc);
        s1[o][xc] = a.x; s1[o][xc + 1] = a.y; s1[o][xc + 2] = a.z; s1[o][xc + 3] = a.w;
        float4 b = *(const float4*)(p2 + o * 64 + xc);
        s2[o][xc] = b.x; s2[o][xc + 1] = b.y; s2[o][xc + 2] = b.z; s2[o][xc + 3] = b.w;
    }
    __syncthreads();
    float2* dst = wc + ((size_t)h * 64) * 4096 + (size_t)e * 64;
    for (int i = tid; i < 4096; i += 256) {
        int x = i >> 6, o = i & 63;
        dst[(size_t)x * 4096 + o] = make_float2(s1[o][x], s2[o][x]);
    }
}

// ---------------------------------------------------------------------------
// Radix-4 partial DFT, sized for the backend's hard 128-VGPR budget:
//  - v2/v5/v6 lesson: allocator pins VGPR=128 (default 4-waves/EU target)
//    regardless of LDS occupancy or __launch_bounds__; any mandatory live
//    set near 128 + scheduler hoisting of unrolled ds_reads -> accumulator
//    spill (~1 GB scratch, 10% VALUBusy, 450+ us).
//    Fix: mandatory live ~84 regs (48 acc + 16 x + 8 tw-prefetch + addr):
//    twiddles come from LDS (v0's bank-rotated layout, double-buffered),
//    and prefetch loads write DIRECTLY into consumed regs (no shadow copies).
//  - grid (b, h, z): one block = full 512 t' for one signal. No split-K.
//  - 512 threads = 2 subs x 256; sub s owns t' in [256s, 256s+256),
//    16 rounds of 16 t'.
//  - compute thread (eg,g): e-tile 4, mode-quad 4g..4g+3, 48 accumulators.
//  - single barrier per round: stage y(butterfly)+tw -> sync -> prefetch
//    next round into (c*, tp*) -> 16-tt FMA block.
//  - 2-sub reduce in LDS (aliases y_s), direct write to Gq/Gk.
__global__ __launch_bounds__(512, 1) void k_dft(
    const float* __restrict__ q, const float* __restrict__ k,
    const float* __restrict__ twq, const float* __restrict__ twk,
    float2* __restrict__ Gq, float2* __restrict__ Gk)
{
    int b = blockIdx.x, h = blockIdx.y, z = blockIdx.z;
    const float* src = z ? k : q;
    const float* tws = z ? twk : twq;

    __shared__ float y_s[2][2][16][4][64];    // 64 KB: [buf][sub][t'][comp][e]
    __shared__ float tw_s[2][2][16][144];     // 36 KB: bank-rotated g-slots

    int tid = threadIdx.x;
    int sub = tid >> 8;            // t' half (wave-uniform)
    int st  = tid & 255;
    int tl  = st >> 4;             // staging row / compute e-group (0..15)
    int g   = st & 15;             // staging e-quad / compute mode-quad
    int goff = g * 8 + ((g >> 2) << 2);   // bank-rotated tw slot (2-way max)
    int tbase = sub * 256;

    const float* xbase = src + ((size_t)b * Lseq) * 512 + h * 64;
    const float* xrow0 = xbase + (size_t)(tbase + tl) * 512 + g * 4;

    float a[4][12];
#pragma unroll
    for (int i = 0; i < 4; ++i)
#pragma unroll
        for (int j = 0; j < 12; ++j) a[i][j] = 0.f;

    // prologue: round-0 x quads + twiddle pair (row tl, modes 4g..4g+3)
    float4 c0 = *(const float4*)(xrow0);
    float4 c1 = *(const float4*)(xrow0 + 262144);
    float4 c2 = *(const float4*)(xrow0 + 524288);
    float4 c3 = *(const float4*)(xrow0 + 786432);
    const float* tsrc = tws + (size_t)(tbase + tl) * 128 + g * 8;
    float4 tp0 = *(const float4*)(tsrc);
    float4 tp1 = *(const float4*)(tsrc + 4);

    for (int rnd = 0; rnd < 16; ++rnd) {
        int buf = rnd & 1;
        {   // butterfly + stage into y_s[buf]; stage twiddles into tw_s[buf]
            float4 sa, sb, y0, y2, pp, qq;
            sa.x = c0.x + c2.x; sa.y = c0.y + c2.y; sa.z = c0.z + c2.z; sa.w = c0.w + c2.w;
            sb.x = c1.x + c3.x; sb.y = c1.y + c3.y; sb.z = c1.z + c3.z; sb.w = c1.w + c3.w;
            y0.x = sa.x + sb.x; y0.y = sa.y + sb.y; y0.z = sa.z + sb.z; y0.w = sa.w + sb.w;
            y2.x = sa.x - sb.x; y2.y = sa.y - sb.y; y2.z = sa.z - sb.z; y2.w = sa.w - sb.w;
            pp.x = c0.x - c2.x; pp.y = c0.y - c2.y; pp.z = c0.z - c2.z; pp.w = c0.w - c2.w;
            qq.x = c1.x - c3.x; qq.y = c1.y - c3.y; qq.z = c1.z - c3.z; qq.w = c1.w - c3.w;
            *(float4*)&y_s[buf][sub][tl][0][g * 4] = y0;
            *(float4*)&y_s[buf][sub][tl][1][g * 4] = y2;
            *(float4*)&y_s[buf][sub][tl][2][g * 4] = pp;
            *(float4*)&y_s[buf][sub][tl][3][g * 4] = qq;
            *(float4*)&tw_s[buf][sub][tl][goff]     = tp0;
            *(float4*)&tw_s[buf][sub][tl][goff + 4] = tp1;
        }
        __syncthreads();
        if (rnd < 15) {   // prefetch next round DIRECTLY into consumed regs
            const float* p = xrow0 + (size_t)(rnd + 1) * (16 * 512);
            c0 = *(const float4*)(p);
            c1 = *(const float4*)(p + 262144);
            c2 = *(const float4*)(p + 524288);
            c3 = *(const float4*)(p + 786432);
            const float* tr = tws + (size_t)(tbase + (rnd + 1) * 16 + tl) * 128 + g * 8;
            tp0 = *(const float4*)(tr);
            tp1 = *(const float4*)(tr + 4);
        }
#pragma unroll
        for (int tt = 0; tt < 16; ++tt) {
            float4 Y0 = *(float4*)&y_s[buf][sub][tt][0][tl * 4];
            float4 Y2 = *(float4*)&y_s[buf][sub][tt][1][tl * 4];
            float4 Pv = *(float4*)&y_s[buf][sub][tt][2][tl * 4];
            float4 Qv = *(float4*)&y_s[buf][sub][tt][3][tl * 4];
            float4 w0 = *(float4*)&tw_s[buf][sub][tt][goff];      // c0,s0,c1,s1
            float4 w1 = *(float4*)&tw_s[buf][sub][tt][goff + 4];  // c2,s2,c3,s3
            const float* y0a = (const float*)&Y0;
            const float* y2a = (const float*)&Y2;
            const float* pa  = (const float*)&Pv;
            const float* qa  = (const float*)&Qv;
#pragma unroll
            for (int i = 0; i < 4; ++i) {
                a[i][0]  += y0a[i] * w0.x;  a[i][1]  += y0a[i] * w0.y;
                a[i][2]  += y2a[i] * w1.x;  a[i][3]  += y2a[i] * w1.y;
                a[i][4]  += pa[i]  * w0.z;  a[i][5]  += qa[i]  * w0.w;
                a[i][6]  += pa[i]  * w0.w;  a[i][7]  += qa[i]  * w0.z;
                a[i][8]  += pa[i]  * w1.z;  a[i][9]  += qa[i]  * w1.w;
                a[i][10] += pa[i]  * w1.w;  a[i][11] += qa[i]  * w1.z;
            }
        }
    }

    __syncthreads();   // y_s free for reduce

    // combine accumulators to complex G: per thread 4e x 4 modes = 8 float4
    float4 gvf[8];
#pragma unroll
    for (int i = 0; i < 4; ++i) {
        gvf[i * 2 + 0] = make_float4(a[i][0], -a[i][1], a[i][4] - a[i][5], -(a[i][6] + a[i][7]));
        gvf[i * 2 + 1] = make_float4(a[i][2], -a[i][3], a[i][8] + a[i][9], a[i][11] - a[i][10]);
    }

    // 2-sub reduce in LDS (XOR-swizzled float4 slots for full-rate banks)
    float4* red = (float4*)y_s;              // 256 threads x 8 float4 = 32 KB
    int rbase = st * 8;
    int sx = st & 7;
    if (sub == 1) {
#pragma unroll
        for (int j = 0; j < 8; ++j) red[rbase + (j ^ sx)] = gvf[j];
    }
    __syncthreads();
    if (sub == 0) {
#pragma unroll
        for (int j = 0; j < 8; ++j) {
            float4 r = red[rbase + (j ^ sx)];
            gvf[j].x += r.x; gvf[j].y += r.y; gvf[j].z += r.z; gvf[j].w += r.w;
        }
        float4* Gd4 = (float4*)((z ? Gk : Gq) + (size_t)(b * 8 + h) * 4096);
#pragma unroll
        for (int i = 0; i < 4; ++i) {
            Gd4[(tl * 4 + i) * 32 + 2 * g + 0] = gvf[i * 2 + 0];
            Gd4[(tl * 4 + i) * 32 + 2 * g + 1] = gvf[i * 2 + 1];
        }
    }
}

// ---------------------------------------------------------------------------
// Per (b,h): freq-domain projection of q,k; S = Q^T K; tanh; U = T K.
__global__ __launch_bounds__(256) void k_core(
    const float2* __restrict__ Gq, const float2* __restrict__ Gk,
    const float* __restrict__ wqw, const float* __restrict__ wqb,
    const float* __restrict__ wkw, const float* __restrict__ wkb,
    const int* __restrict__ iq, const int* __restrict__ ikv,
    float2* __restrict__ U)
{
    int b = blockIdx.x, h = blockIdx.y;
    int tid = threadIdx.x;
    __shared__ float2 bufA[4096];
    __shared__ float2 Qf[4096];
    __shared__ float2 Kf[4096];
    __shared__ float  Wm[4096];
    __shared__ float  bias_s[64];
    __shared__ int    idx_s[64];

    size_t gb = (size_t)(b * 8 + h) * 4096;

    for (int z = 0; z < 2; ++z) {
        const float* Wsrc = z ? wkw : wqw;
        const float* bsrc = z ? wkb : wqb;
        const int*   isrc = z ? ikv : iq;
        const float2* Gsrc = (z ? Gk : Gq) + gb;
        float2* dst = z ? Kf : Qf;
        if (tid < 64) { bias_s[tid] = bsrc[tid]; idx_s[tid] = isrc[tid]; }
#pragma unroll
        for (int j = 0; j < 4; ++j)
            ((float4*)Wm)[tid + 256 * j] = ((const float4*)Wsrc)[tid + 256 * j];
#pragma unroll
        for (int j = 0; j < 8; ++j)
            ((float4*)bufA)[tid + 256 * j] = ((const float4*)Gsrc)[tid + 256 * j];
        __syncthreads();
        {
            int eg = tid >> 4, xg = tid & 15;
            float2 acc[4][4];
#pragma unroll
            for (int i = 0; i < 4; ++i)
#pragma unroll
                for (int j = 0; j < 4; ++j) acc[i][j] = make_float2(0.f, 0.f);
            for (int ep = 0; ep < 64; ++ep) {
                float wv[4]; float2 gvv[4];
#pragma unroll
                for (int i = 0; i < 4; ++i) wv[i] = Wm[(eg * 4 + i) * 64 + ep];
#pragma unroll
                for (int j = 0; j < 4; ++j) gvv[j] = bufA[ep * 64 + xg + 16 * j];
#pragma unroll
                for (int i = 0; i < 4; ++i)
#pragma unroll
                    for (int j = 0; j < 4; ++j) {
                        acc[i][j].x += wv[i] * gvv[j].x;
                        acc[i][j].y += wv[i] * gvv[j].y;
                    }
            }
#pragma unroll
            for (int j = 0; j < 4; ++j) {
                int x = xg + 16 * j;
                float bz = (idx_s[x] == 0) ? 2048.0f : 0.0f;
#pragma unroll
                for (int i = 0; i < 4; ++i) {
                    float2 v = acc[i][j];
                    v.x += bz * bias_s[eg * 4 + i];
                    dst[(eg * 4 + i) * 64 + x] = v;
                }
            }
        }
        __syncthreads();
    }

    {
        int xg = tid & 15, yg = tid >> 4;
        float2 acc[4][4];
#pragma unroll
        for (int i = 0; i < 4; ++i)
#pragma unroll
            for (int j = 0; j < 4; ++j) acc[i][j] = make_float2(0.f, 0.f);
        for (int e = 0; e < 64; ++e) {
            float2 qv[4], kv[4];
#pragma unroll
            for (int i = 0; i < 4; ++i) qv[i] = Qf[e * 64 + xg + 16 * i];
#pragma unroll
            for (int j = 0; j < 4; ++j) kv[j] = Kf[e * 64 + yg * 4 + j];
#pragma unroll
            for (int i = 0; i < 4; ++i)
#pragma unroll
                for (int j = 0; j < 4; ++j) {
                    acc[i][j].x += qv[i].x * kv[j].x - qv[i].y * kv[j].y;
                    acc[i][j].y += qv[i].x * kv[j].y + qv[i].y * kv[j].x;
                }
        }
#pragma unroll
        for (int i = 0; i < 4; ++i)
#pragma unroll
            for (int j = 0; j < 4; ++j)
                bufA[(yg * 4 + j) * 64 + xg + 16 * i] =
                    make_float2(tanhf(acc[i][j].x), tanhf(acc[i][j].y));
    }
    __syncthreads();

    {
        int xg = tid & 15, eg = tid >> 4;
        float2 acc[4][4];
#pragma unroll
        for (int i = 0; i < 4; ++i)
#pragma unroll
            for (int j = 0; j < 4; ++j) acc[i][j] = make_float2(0.f, 0.f);
        for (int y = 0; y < 64; ++y) {
            float2 kv[4], tv[4];
#pragma unroll
            for (int i = 0; i < 4; ++i) kv[i] = Kf[(eg * 4 + i) * 64 + y];
#pragma unroll
            for (int j = 0; j < 4; ++j) tv[j] = bufA[y * 64 + xg + 16 * j];
#pragma unroll
            for (int i = 0; i < 4; ++i)
#pragma unroll
                for (int j = 0; j < 4; ++j) {
                    acc[i][j].x += tv[j].x * kv[i].x - tv[j].y * kv[i].y;
                    acc[i][j].y += tv[j].x * kv[i].y + tv[j].y * kv[i].x;
                }
        }
        float2* Ud = U + gb;
#pragma unroll
        for (int i = 0; i < 4; ++i)
#pragma unroll
            for (int j = 0; j < 4; ++j)
                Ud[(eg * 4 + i) * 64 + xg + 16 * j] = acc[i][j];
    }
}

// ---------------------------------------------------------------------------
// Per (h,x): X[b,o] = sum_e U[b,e] wc[e,o]; fold irfft scales; A[b][h][o][x]=(P,Q).
__global__ __launch_bounds__(128) void k_apply_w(
    const float2* __restrict__ U, const float2* __restrict__ wc,
    const int* __restrict__ iq, float2* __restrict__ A)
{
    int x = blockIdx.x, h = blockIdx.y;
    int tid = threadIdx.x;
    __shared__ float2 wl[4096];
    __shared__ float2 ul[16][65];
    const float4* wsrc = (const float4*)(wc + (size_t)(h * 64 + x) * 4096);
#pragma unroll
    for (int j = 0; j < 16; ++j)
        ((float4*)wl)[tid + 128 * j] = wsrc[tid + 128 * j];
#pragma unroll
    for (int j = 0; j < 8; ++j) {
        int idx = tid + 128 * j;
        int bb = idx >> 6, e = idx & 63;
        ul[bb][e] = U[((size_t)(bb * 8 + h) * 64 + e) * 64 + x];
    }
    __syncthreads();
    int bb = tid >> 3, og = tid & 7;
    float2 acc[8];
#pragma unroll
    for (int j = 0; j < 8; ++j) acc[j] = make_float2(0.f, 0.f);
    for (int e = 0; e < 64; ++e) {
        float2 u = ul[bb][e];
#pragma unroll
        for (int j = 0; j < 8; ++j) {
            float2 wv = wl[e * 64 + og + 8 * j];
            acc[j].x += u.x * wv.x - u.y * wv.y;
            acc[j].y += u.x * wv.y + u.y * wv.x;
        }
    }
    int f = iq[x];
    bool dc = (f == 0) || (2 * f == Lseq);
    float cm = (dc ? 1.0f : 2.0f) * (1.0f / (2048.0f * 262144.0f));
    float2* Ad = A + (size_t)(bb * 8 + h) * 4096;
#pragma unroll
    for (int j = 0; j < 8; ++j) {
        int o = og + 8 * j;
        Ad[o * 64 + x] = make_float2(cm * acc[j].x, dc ? 0.0f : -cm * acc[j].y);
    }
}

// ---------------------------------------------------------------------------
// Radix-4 inverse: out[t'+512j] from U_r/V_r class sums.
// grid (tt:8, h, b), 512 thr: wave = o-slice of 8 (A reads wave-uniform),
// lane = t'. tw tile XOR-swizzled by row (2-way max conflicts).
__global__ __launch_bounds__(512) void k_irfft(
    const float2* __restrict__ A, const float* __restrict__ tw,
    float* __restrict__ out)
{
    int tt = blockIdx.x, h = blockIdx.y, b = blockIdx.z;
    int t0 = tt * 64;
    int tid = threadIdx.x;
    __shared__ float2 A_s[4096];        // [o][x] (P,Q)
    __shared__ float  tw_s[64][128];    // rows t', XOR-swizzled float4s
    const float4* asrc = (const float4*)(A + (size_t)(b * 8 + h) * 4096);
#pragma unroll
    for (int j = 0; j < 4; ++j)
        ((float4*)A_s)[tid + 512 * j] = asrc[tid + 512 * j];
    {
        int row = tid >> 3, c4b = (tid & 7) * 4;
        const float4* s = (const float4*)(tw + (size_t)(t0 + row) * 128);
        float4* drow = (float4*)&tw_s[row][0];
#pragma unroll
        for (int kk = 0; kk < 4; ++kk) {
            int c4 = c4b + kk;
            drow[c4 ^ (row & 31)] = s[c4];
        }
    }
    __syncthreads();
    int tl = tid & 63, ow = tid >> 6;    // o = ow*8 + i
    float U0[8], U1[8], V1[8], U2[8], U3[8], V3[8];
#pragma unroll
    for (int i = 0; i < 8; ++i) { U0[i]=U1[i]=V1[i]=U2[i]=U3[i]=V3[i]=0.f; }
    const float4* trow = (const float4*)&tw_s[tl][0];
    int sw = tl & 31;
#pragma unroll
    for (int g = 0; g < 16; ++g) {
        float4 w0 = trow[(2 * g) ^ sw];       // c(4g),s(4g),c(4g+1),s(4g+1)
        float4 w1 = trow[(2 * g + 1) ^ sw];   // c(4g+2),s(4g+2),c(4g+3),s(4g+3)
#pragma unroll
        for (int i = 0; i < 8; ++i) {
            const float4* ap = (const float4*)&A_s[(ow * 8 + i) * 64 + 4 * g];
            float4 a0 = ap[0];   // P0,Q0,P1,Q1
            float4 a1 = ap[1];   // P2,Q2,P3,Q3
            U0[i] += a0.x * w0.x + a0.y * w0.y;
            U1[i] += a0.z * w0.z + a0.w * w0.w;
            V1[i] += a0.w * w0.z - a0.z * w0.w;
            U2[i] += a1.x * w1.x + a1.y * w1.y;
            U3[i] += a1.z * w1.z + a1.w * w1.w;
            V3[i] += a1.w * w1.z - a1.z * w1.w;
        }
    }
    float* op = out + ((size_t)(b * 8 + h) * 64 + ow * 8) * Lseq + t0 + tl;
#pragma unroll
    for (int i = 0; i < 8; ++i) {
        float u0 = U0[i], u1 = U1[i], v1 = V1[i], u2 = U2[i], u3 = U3[i], v3 = V3[i];
        op[(size_t)i * Lseq +    0] = u0 + u1 + u2 + u3;
        op[(size_t)i * Lseq +  512] = u0 + v1 - u2 - v3;
        op[(size_t)i * Lseq + 1024] = u0 - u1 + u2 - u3;
        op[(size_t)i * Lseq + 1536] = u0 - v1 - u2 + v3;
    }
}

// ---------------------------------------------------------------------------
extern "C" void kernel_launch(void* const* d_in, const int* in_sizes, int n_in,
                              void* d_out, int out_size, void* d_ws, size_t ws_size,
                              hipStream_t stream)
{
    const float* q    = (const float*)d_in[0];
    const float* k    = (const float*)d_in[1];
    const float* wq_w = (const float*)d_in[3];
    const float* wq_b = (const float*)d_in[4];
    const float* wk_w = (const float*)d_in[5];
    const float* wk_b = (const float*)d_in[6];
    const float* w1   = (const float*)d_in[9];
    const float* w2   = (const float*)d_in[10];
    const int*   iq   = (const int*)d_in[11];
    const int*   ikv  = (const int*)d_in[12];
    float* out = (float*)d_out;

    char* ws = (char*)d_ws;
    float2* twq = (float2*)(ws + OFF_TWQ);
    float2* twk = (float2*)(ws + OFF_TWK);
    float2* Gq  = (float2*)(ws + OFF_GQ);
    float2* Gk  = (float2*)(ws + OFF_GK);
    float2* Uw  = (float2*)(ws + OFF_U);
    float2* Aw  = (float2*)(ws + OFF_A);
    float2* wc  = (float2*)(ws + OFF_WC);

    k_twiddle<<<128, 256, 0, stream>>>(iq, ikv, twq, twk);
    k_dft<<<dim3(16, 8, 2), 512, 0, stream>>>(q, k, (const float*)twq,
                                              (const float*)twk, Gq, Gk);
    k_core<<<dim3(16, 8), 256, 0, stream>>>(Gq, Gk, wq_w, wq_b, wk_w, wk_b,
                                            iq, ikv, Uw);
    k_wtrans<<<dim3(8, 64), 256, 0, stream>>>(w1, w2, wc);
    k_apply_w<<<dim3(64, 8), 128, 0, stream>>>(Uw, wc, iq, Aw);
    k_irfft<<<dim3(8, 8, 16), 512, 0, stream>>>(Aw, (const float*)twq, out);
}